// Round 8
// baseline (3459.807 us; speedup 1.0000x reference)
//
#include <hip/hip_runtime.h>
#include <math.h>

#define EMBD 300
#define HROW 304     // fp16 h row stride (elements) = 608 B; cols 300-303 = 0
#define LDF  304     // fp32 junction-phase row stride
#define KEXT 320     // extended K: 304 h(+pad) + 1 bias + 6 ee1 + 3 ee2 + 6 pad
#define BCH  80      // B cols per jt chunk (4 chunks of 80 = 320)
#define BSTR 40      // LDS B row stride (halves): 80 B
#define TS2  312     // LDS C-tile row stride (halves): 624 B
#define SPR  608     // spart row stride (halves): [0..299]=sum, [304..603]=sumsq
#define NTAB 24      // layer-0 tables: 9 htab@Wx^T + 15 ext (bt 0..4 x bd 0..2)
#define CE(a,b) (((a)+(b)-1)/(b))

typedef _Float16 h16;
typedef __attribute__((ext_vector_type(8))) _Float16 half8;
typedef __attribute__((ext_vector_type(4))) float f32x4;

// ---------------- utility / CSR kernels ----------------
__global__ void k_diag(float* out, int n, float v){
  int i = blockIdx.x*256 + threadIdx.x;
  if (i < n) out[i] = v;
}
// degcnt = 0, counts = 1 (self-loop) in one pass
__global__ void k_init_deg(int* __restrict__ deg, int* __restrict__ cnts, int N){
  int i = blockIdx.x*256 + threadIdx.x;
  if (i < N){ deg[i] = 0; cnts[i] = 1; }
}
// one pass over edges: src-degree (for dinv) + dst-counts (for CSR)
__global__ void k_count_both(const int* __restrict__ ei, int E,
                             int* __restrict__ deg, int* __restrict__ cnts){
  int e = blockIdx.x*256 + threadIdx.x;
  if (e < E){
    atomicAdd(&deg[ei[e]], 1);
    atomicAdd(&cnts[ei[E + e]], 1);
  }
}
__global__ void k_dinv(const int* __restrict__ deg, float* __restrict__ dinv, int N){
  int i = blockIdx.x*256 + threadIdx.x;
  if (i < N) dinv[i] = 1.0f / sqrtf((float)(deg[i] + 1));   // +1 self-loop
}
__global__ void k_count_ids(const int* __restrict__ ids, int n, int* __restrict__ counts){
  int i = blockIdx.x*256 + threadIdx.x;
  if (i < n) atomicAdd(&counts[ids[i]], 1);
}
__global__ void k_scan_block(const int* __restrict__ in, int M, int* __restrict__ out, int* __restrict__ bsum){
  __shared__ int s[256];
  int t = threadIdx.x, i = blockIdx.x*256 + t;
  int v = (i < M) ? in[i] : 0;
  s[t] = v; __syncthreads();
  for (int off = 1; off < 256; off <<= 1){
    int x = (t >= off) ? s[t-off] : 0;
    __syncthreads();
    s[t] += x;
    __syncthreads();
  }
  if (i < M) out[i] = s[t] - v;
  if (t == 255) bsum[blockIdx.x] = s[255];
}
__global__ void k_scan_sums(int* __restrict__ bsum, int B){   // B <= 1024
  __shared__ int s[1024];
  int t = threadIdx.x;
  int v = (t < B) ? bsum[t] : 0;
  s[t] = v; __syncthreads();
  for (int off = 1; off < 1024; off <<= 1){
    int x = (t >= off) ? s[t-off] : 0;
    __syncthreads();
    s[t] += x;
    __syncthreads();
  }
  if (t < B) bsum[t] = s[t] - v;
}
__global__ void k_scan_add(int* __restrict__ out, const int* __restrict__ bsum, int M){
  int i = blockIdx.x*256 + threadIdx.x;
  if (i < M) out[i] += bsum[blockIdx.x];
}
// entries payload: src | bt<<20 | bd<<23   (src < 2^20)
__global__ void k_fill_edges(const int* __restrict__ ei, const int* __restrict__ ea, int E, int N,
                             const int* __restrict__ offs, int* __restrict__ cur, int* __restrict__ entries){
  int e = blockIdx.x*256 + threadIdx.x;
  if (e < E){
    int s  = ei[e];
    int d  = ei[E + e];
    int bt = ea[2*e], bd = ea[2*e + 1];
    int pos = offs[d] + atomicAdd(&cur[d], 1);
    entries[pos] = s | (bt << 20) | (bd << 23);
  } else if (e < E + N){
    int i = e - E;                          // self-loop: bond type 4, dir 0
    int pos = offs[i] + atomicAdd(&cur[i], 1);
    entries[pos] = i | (4 << 20);
  }
}
__global__ void k_fill_rows(const int* __restrict__ ids, int n, const int* __restrict__ offs,
                            int* __restrict__ cur, int* __restrict__ entries){
  int i = blockIdx.x*256 + threadIdx.x;
  if (i < n){
    int g = ids[i];
    int pos = offs[g] + atomicAdd(&cur[g], 1);
    entries[pos] = i;
  }
}
// pool permutation: node i -> slot perm[i] (slots of a graph are contiguous)
__global__ void k_fill_perm(const int* __restrict__ ids, int n, const int* __restrict__ offs,
                            int* __restrict__ cur, int* __restrict__ perm){
  int i = blockIdx.x*256 + threadIdx.x;
  if (i < n){
    int g = ids[i];
    perm[i] = offs[g] + atomicAdd(&cur[g], 1);
  }
}

// ---------------- model kernels ----------------
// h0 has only 9 distinct rows (x entries are in [0,3)): htab[p] = ae1[p/3]+ae2[p%3]
__global__ void k_htab(const float* __restrict__ ae1, const float* __restrict__ ae2,
                       h16* __restrict__ htab){
  int p = blockIdx.x;                 // 0..8
  int a = p / 3, b = p % 3;
  int t = threadIdx.x;
  h16* d = htab + (size_t)p*HROW;
  for (int c = t; c < HROW; c += 256)
    d[c] = (c < EMBD) ? (h16)(ae1[(size_t)a*EMBD + c] + ae2[(size_t)b*EMBD + c]) : (h16)0.f;
}
__global__ void k_pidx(const int* __restrict__ x, unsigned char* __restrict__ pidx, int N){
  int i = blockIdx.x*256 + threadIdx.x;
  if (i < N) pidx[i] = (unsigned char)(x[2*i]*3 + x[2*i+1]);
}
// layer-0 tables: ctab[q][o].  q<9: htab[q] @ Wx[o]^T (fp16 ops, f32 accum).
// q>=9: Wx[o][304] + Wx[o][305+bt] + Wx[o][311+bd].
__global__ void k_ctab(const h16* __restrict__ htabG, const h16* __restrict__ Wx,
                       float* __restrict__ ctab){
  int q = blockIdx.x, t = threadIdx.x;
  float* d = ctab + (size_t)q*HROW;
  if (q < 9){
    const h16* hr = htabG + (size_t)q*HROW;
    for (int o = t; o < HROW; o += 256){
      float s = 0.f;
      if (o < EMBD){
        const h16* wr = Wx + (size_t)o*KEXT;
        for (int k = 0; k < EMBD; k++)
          s += (float)hr[k] * (float)wr[k];
      }
      d[o] = s;
    }
  } else {
    int bt = (q - 9) / 3, bd = (q - 9) % 3;
    for (int o = t; o < HROW; o += 256){
      float s = 0.f;
      if (o < EMBD){
        const h16* wr = Wx + (size_t)o*KEXT;
        s = (float)wr[304] + (float)wr[305 + bt] + (float)wr[311 + bd];
      }
      d[o] = s;
    }
  }
}

// extended weights (fp16): Wx[l][o][k], o,k in [0,KEXT)
// k<300: W[o][k]; k==304: b[o]; 305..310: ee1; 311..313: ee2; else 0
__global__ void k_wext(const float* __restrict__ W, const float* __restrict__ b,
                       const float* __restrict__ ee1, const float* __restrict__ ee2,
                       h16* __restrict__ out){
  int l = blockIdx.y, o = blockIdx.x, t = threadIdx.x;
  h16* d = out + ((size_t)l*KEXT + o)*KEXT;
  for (int k = t; k < KEXT; k += 256){
    float v = 0.f;
    if (o < EMBD){
      if      (k < EMBD)            v = W[(size_t)l*EMBD*EMBD + (size_t)o*EMBD + k];
      else if (k == 304)            v = b[l*EMBD + o];
      else if (k >= 305 && k < 311) v = ee1[((size_t)l*6 + (k-305))*EMBD + o];
      else if (k >= 311 && k < 314) v = ee2[((size_t)l*3 + (k-311))*EMBD + o];
    }
    d[k] = (h16)v;
  }
}
// plain fp16 zero-pad of jct_W: wjx[l][o][k], 320x320, grid (KEXT, 2)
__global__ void k_wpad(const float* __restrict__ W, h16* __restrict__ out){
  int l = blockIdx.y, o = blockIdx.x, t = threadIdx.x;
  h16* d = out + ((size_t)l*KEXT + o)*KEXT;
  for (int k = t; k < KEXT; k += 256)
    d[k] = (h16)((o < EMBD && k < EMBD) ? W[(size_t)l*EMBD*EMBD + (size_t)o*EMBD + k] : 0.f);
}
// f32 rows [M][LDF] -> fp16 rows [Mpad][KEXT] (zero-padded), for MFMA B operand
__global__ void k_f16rows(const float* __restrict__ src, int M, h16* __restrict__ dst){
  int r = blockIdx.x, t = threadIdx.x;
  h16* d = dst + (size_t)r*KEXT;
  for (int k = t; k < KEXT; k += 256)
    d[k] = (h16)((r < M && k < EMBD) ? src[(size_t)r*LDF + k] : 0.f);
}

// BN affine from stats: fp32 (for pooled rows) + fp16 (for gather).
// Also RE-ZEROS stats for the next layer (drops the per-layer memset).
__global__ void k_bn_coef(float* __restrict__ stats, const float* __restrict__ gamma,
                          const float* __restrict__ beta, float* __restrict__ coef,
                          h16* __restrict__ coefh, float invN){
  int c = blockIdx.x*256 + threadIdx.x;
  if (c >= KEXT) return;
  float sc = 0.f, sh = 0.f;
  if (c < EMBD){
    float mu  = stats[c]*invN;
    float var = stats[EMBD + c]*invN - mu*mu;
    sc = gamma[c]*rsqrtf(var + 1e-5f);
    sh = beta[c] - mu*sc;
    stats[c] = 0.f; stats[EMBD + c] = 0.f;
  }
  if (c < HROW){ coef[c] = sc; coef[HROW + c] = sh; }
  coefh[c] = (h16)sc; coefh[KEXT + c] = (h16)sh;
}

// reduce per-block fp16 stat partials -> stats[600] (f32)
__global__ void k_red_stats(const h16* __restrict__ spart, int nb, float* __restrict__ stats){
  int t = threadIdx.x;
  int c1 = t + 256;                      // valid only for t < 44
  float a0 = 0.f, q0 = 0.f, a1 = 0.f, q1 = 0.f;
  for (int b = blockIdx.x; b < nb; b += gridDim.x){
    const h16* sp = spart + (size_t)b*SPR;
    a0 += (float)sp[t];
    q0 += (float)sp[304 + t];
    if (c1 < EMBD){ a1 += (float)sp[c1]; q1 += (float)sp[304 + c1]; }
  }
  if (t < EMBD){ atomicAdd(&stats[t], a0); atomicAdd(&stats[EMBD + t], q0); }
  if (c1 < EMBD){ atomicAdd(&stats[c1], a1); atomicAdd(&stats[EMBD + c1], q1); }
}

// ---- fused layer (layers 1-4): fixed-8 fan-out gather -> MFMA -> BN stats ----
// Gather/MFMA unchanged from round 4 (at roofline). NEW: optional perm on the
// writeout (layer 4 writes pool-sorted so pooling becomes a streaming read).
template<int RELU>
__global__ void __launch_bounds__(256)
k_layer(const h16* __restrict__ hRaw, const h16* __restrict__ coefh,
        const float* __restrict__ dinv,
        const int* __restrict__ offs, const int* __restrict__ counts,
        const int* __restrict__ entries, const h16* __restrict__ Wx,
        h16* __restrict__ hOut, int N, h16* __restrict__ spart,
        const int* __restrict__ perm)
{
  __shared__ h16  tile[64][TS2];       // 39.9 KB persistent C tile
  __shared__ h16  Bs[BCH][BSTR];       //  6.4 KB B chunk (80 cols x 32 k)
  __shared__ float sred[2*HROW];       //  2.4 KB BN partials
  __shared__ int   rstart[64];
  __shared__ int   rcnt[64];
  __shared__ int   prow[64];
  __shared__ float dvv[64];

  int tid = threadIdx.x;
  int wid = tid >> 6, lane = tid & 63;
  int m16 = lane & 15, ko = lane >> 4;
  long row0 = (long)blockIdx.x * 64;

  if (tid < 64){
    long g = row0 + tid;
    int o = 0, c = 0; float d = 0.f; int pr = (int)g;
    if (g < N){
      o = offs[g]; c = counts[g]; d = dinv[g];
      if (perm) pr = perm[g];
    }
    rstart[tid] = o; rcnt[tid] = c; dvv[tid] = d; prow[tid] = pr;
  }
  for (int i = tid; i < 2*HROW; i += 256) sred[i] = 0.f;
  __syncthreads();

  int lr = wid*16 + m16;
  int myStart = rstart[lr], myCnt = rcnt[lr];
  float di = dvv[lr];

  // ---- prefetch up to 8 edge descriptors + weights ----
  int srcA[8]; float wvA[8]; int eA[8];
  #pragma unroll
  for (int j = 0; j < 8; j++){
    int e = entries[myStart + j];               // bounded over-read ok (within ws)
    bool act = j < myCnt;
    int s = act ? (e & 0xFFFFF) : N;            // row N is all-zero
    float wv = dinv[act ? s : 0];
    wvA[j] = act ? wv : 0.f;
    srcA[j] = s; eA[j] = e;
  }
  float ext[8] = {0,0,0,0,0,0,0,0};
  if (ko >= 2){
    int extbase = (ko - 2)*8;
    #pragma unroll
    for (int j = 0; j < 8; j++){
      unsigned msk = 1u | (1u << (1 + ((eA[j] >> 20) & 7))) | (1u << (7 + ((eA[j] >> 23) & 3)));
      #pragma unroll
      for (int c = 0; c < 8; c++)
        ext[c] += ((msk >> (extbase + c)) & 1u) ? wvA[j] : 0.f;
    }
  }
  half8 wvh[8];
  #pragma unroll
  for (int j = 0; j < 8; j++){
    _Float16 w = (_Float16)wvA[j];
    #pragma unroll
    for (int c = 0; c < 8; c++) wvh[j][c] = w;
  }

  half8 acc[10];
  #pragma unroll
  for (int k = 0; k < 10; k++) acc[k] = (half8)(_Float16)0;

  // ---- rare overflow: rows with cnt > 8 (per-lane divergent) ----
  if (__any(myCnt > 8)){
    for (int j = 8; j < myCnt; j++){
      int e = entries[myStart + j];
      int s = e & 0xFFFFF;
      float wv = dinv[s];
      if (ko >= 2){
        int extbase = (ko - 2)*8;
        unsigned msk = 1u | (1u << (1 + ((e >> 20) & 7))) | (1u << (7 + ((e >> 23) & 3)));
        #pragma unroll
        for (int c = 0; c < 8; c++)
          ext[c] += ((msk >> (extbase + c)) & 1u) ? wv : 0.f;
      }
      _Float16 wh = (_Float16)wv;
      half8 w8;
      #pragma unroll
      for (int c = 0; c < 8; c++) w8[c] = wh;
      #pragma unroll
      for (int k = 0; k < 10; k++){
        if (k == 9 && ko >= 2) break;
        half8 sck = *(const half8*)&coefh[k*32 + ko*8];
        half8 shk = *(const half8*)&coefh[KEXT + k*32 + ko*8];
        half8 x = *(const half8*)(hRaw + (size_t)s*HROW + k*32 + ko*8);
        half8 y = sck*x + shk;
        if (RELU){
          #pragma unroll
          for (int c = 0; c < 8; c++) y[c] = y[c] > (_Float16)0 ? y[c] : (_Float16)0;
        }
        acc[k] += w8*y;
      }
    }
  }

  // ---- main gather: chunk-outer, fixed 8 edges inner (8 loads in flight) ----
  #pragma unroll
  for (int k = 0; k < 9; k++){
    half8 sck = *(const half8*)&coefh[k*32 + ko*8];
    half8 shk = *(const half8*)&coefh[KEXT + k*32 + ko*8];
    half8 a = acc[k];
    #pragma unroll
    for (int j = 0; j < 8; j++){
      half8 x = *(const half8*)(hRaw + (size_t)srcA[j]*HROW + k*32 + ko*8);
      half8 y = sck*x + shk;
      if (RELU){
        #pragma unroll
        for (int c = 0; c < 8; c++) y[c] = y[c] > (_Float16)0 ? y[c] : (_Float16)0;
      }
      a += wvh[j]*y;
    }
    acc[k] = a;
  }
  { // k = 9: ko<2 covers cols 288-303 (coef 300-303 = 0); ko>=2 = ext scalars
    half8 a = acc[9];
    if (ko < 2){
      half8 sck = *(const half8*)&coefh[288 + ko*8];
      half8 shk = *(const half8*)&coefh[KEXT + 288 + ko*8];
      #pragma unroll
      for (int j = 0; j < 8; j++){
        half8 x = *(const half8*)(hRaw + (size_t)srcA[j]*HROW + 288 + ko*8);
        half8 y = sck*x + shk;
        if (RELU){
          #pragma unroll
          for (int c = 0; c < 8; c++) y[c] = y[c] > (_Float16)0 ? y[c] : (_Float16)0;
        }
        a += wvh[j]*y;
      }
    } else {
      #pragma unroll
      for (int c = 0; c < 8; c++) a[c] += (_Float16)ext[c];
    }
    acc[9] = a;
  }

  // scale by dinv[dst]
  half8 afr[10];
  {
    _Float16 dh = (_Float16)di;
    half8 d8;
    #pragma unroll
    for (int c = 0; c < 8; c++) d8[c] = dh;
    #pragma unroll
    for (int k = 0; k < 10; k++) afr[k] = acc[k] * d8;
  }

  // ---- GEMM over 4 col-chunks of 80; C staged to persistent LDS tile ----
  int cr = ko * 4;
  #pragma unroll
  for (int jt = 0; jt < 4; jt++){
    f32x4 a2[5];
    #pragma unroll
    for (int j = 0; j < 5; j++) a2[j] = (f32x4){0.f,0.f,0.f,0.f};
    for (int k0 = 0; k0 < 10; k0++){
      __syncthreads();
      for (int idx = tid; idx < 320; idx += 256){
        int o = idx >> 2, qd = (idx & 3) * 8;
        *(half8*)&Bs[o][qd] = *(const half8*)(Wx + (size_t)(jt*BCH + o)*KEXT + k0*32 + qd);
      }
      __syncthreads();
      #pragma unroll
      for (int j = 0; j < 5; j++){
        half8 bfr = *(const half8*)&Bs[j*16 + m16][ko*8];
        a2[j] = __builtin_amdgcn_mfma_f32_16x16x32_f16(afr[k0], bfr, a2[j], 0, 0, 0);
      }
    }
    // BN partials from registers (LDS atomics only)
    #pragma unroll
    for (int j = 0; j < 5; j++){
      int col = jt*BCH + j*16 + m16;
      float s = 0.f, q = 0.f;
      #pragma unroll
      for (int r = 0; r < 4; r++){
        float v = a2[j][r];
        s += v; q += v*v;
      }
      s += __shfl_xor(s, 16, 64); s += __shfl_xor(s, 32, 64);
      q += __shfl_xor(q, 16, 64); q += __shfl_xor(q, 32, 64);
      if (ko == 0 && col < EMBD){
        atomicAdd(&sred[col], s);
        atomicAdd(&sred[HROW + col], q);
      }
    }
    // stage to tile (wave-private rows: no barrier needed)
    #pragma unroll
    for (int j = 0; j < 5; j++){
      int col = jt*BCH + j*16 + m16;
      if (col < HROW){
        #pragma unroll
        for (int r = 0; r < 4; r++)
          tile[wid*16 + cr + r][col] = (h16)a2[j][r];
      }
    }
  }
  __syncthreads();
  // ---- coalesced writeout (608 B rows, each line once; row base via perm) ----
  for (int idx = tid; idx < 64*38; idx += 256){
    int row = idx / 38, c = idx - row*38;
    long grow = row0 + row;
    if (grow < N)
      *(uint4*)(hOut + (size_t)prow[row]*HROW + c*8) = *(const uint4*)&tile[row][c*8];
  }
  // ---- BN partials -> per-block fp16 slab (no global atomics) ----
  h16* sp = spart + (size_t)blockIdx.x*SPR;
  for (int c = tid; c < EMBD; c += 256){
    sp[c]       = (h16)sred[c];
    sp[304 + c] = (h16)sred[HROW + c];
  }
}

// ---- layer 0, table form: out[d] = dinv[d] * sum_q coef_q(d) * ctab[q] ----
__global__ void __launch_bounds__(256)
k_layer0(const unsigned char* __restrict__ pidx, const float* __restrict__ ctab,
         const float* __restrict__ dinv,
         const int* __restrict__ offs, const int* __restrict__ counts,
         const int* __restrict__ entries,
         h16* __restrict__ hOut, int N, h16* __restrict__ spart)
{
  __shared__ float tabs[NTAB][HROW];   // 29.2 KB
  __shared__ float cf[64][NTAB];       //  6.0 KB
  __shared__ float sred[2*HROW];       //  2.4 KB
  int tid = threadIdx.x;
  long row0 = (long)blockIdx.x * 64;

  for (int i = tid; i < NTAB*HROW; i += 256) ((float*)tabs)[i] = ctab[i];
  for (int i = tid; i < 64*NTAB; i += 256) ((float*)cf)[i] = 0.f;
  for (int i = tid; i < 2*HROW; i += 256) sred[i] = 0.f;
  __syncthreads();

  if (tid < 64){
    long g = row0 + tid;
    if (g < N){
      int o = offs[g], c = counts[g];
      float dv = dinv[g];
      float* cr = cf[tid];
      for (int j = 0; j < c; j++){
        int e = entries[o + j];
        int s = e & 0xFFFFF;
        int bt = (e >> 20) & 7, bd = (e >> 23) & 3;
        float wv = dinv[s];
        cr[pidx[s]] += wv;
        cr[9 + bt*3 + bd] += wv;
      }
      #pragma unroll
      for (int q = 0; q < NTAB; q++) cr[q] *= dv;   // fold dinv[dst]
    }
  }
  __syncthreads();

  // output: work item w = (row-group rg of 8 rows) x (16B col-chunk c of 38)
  for (int w = tid; w < 8*38; w += 256){
    int c = w % 38, rg = w / 38;
    float v[8][8];
    #pragma unroll
    for (int r = 0; r < 8; r++)
      #pragma unroll
      for (int cc = 0; cc < 8; cc++) v[r][cc] = 0.f;
    for (int q = 0; q < NTAB; q++){
      float tr[8];
      #pragma unroll
      for (int cc = 0; cc < 8; cc++) tr[cc] = tabs[q][c*8 + cc];
      #pragma unroll
      for (int r = 0; r < 8; r++){
        float co = cf[rg*8 + r][q];
        #pragma unroll
        for (int cc = 0; cc < 8; cc++) v[r][cc] += co * tr[cc];
      }
    }
    float s[8], qq[8];
    #pragma unroll
    for (int cc = 0; cc < 8; cc++){ s[cc] = 0.f; qq[cc] = 0.f; }
    #pragma unroll
    for (int r = 0; r < 8; r++){
      long grow = row0 + rg*8 + r;
      if (grow < N){
        half8 hv;
        #pragma unroll
        for (int cc = 0; cc < 8; cc++){
          float x = v[r][cc];
          hv[cc] = (h16)x;
          s[cc] += x; qq[cc] += x*x;
        }
        *(half8*)(hOut + grow*HROW + c*8) = hv;
      }
    }
    #pragma unroll
    for (int cc = 0; cc < 8; cc++){
      atomicAdd(&sred[c*8 + cc], s[cc]);
      atomicAdd(&sred[HROW + c*8 + cc], qq[cc]);
    }
  }
  __syncthreads();
  h16* sp = spart + (size_t)blockIdx.x*SPR;
  for (int c = tid; c < EMBD; c += 256){
    sp[c]       = (h16)sred[c];
    sp[304 + c] = (h16)sred[HROW + c];
  }
}

// mean-pool over CONTIGUOUS permuted rows + fused BN affine (+ optional mask)
__global__ void k_pool_h(const h16* __restrict__ h, const int* __restrict__ offs,
                         const int* __restrict__ counts,
                         float* __restrict__ out, const float* __restrict__ coef,
                         const float* __restrict__ mask, const float* __restrict__ memb){
  int g = blockIdx.x, t = threadIdx.x, c1 = t + 256;
  int off = offs[g], cnt = counts[g];
  float a0 = 0.f, a1 = 0.f;
  const h16* base = h + (size_t)off*HROW;
  int j = 0;
  for (; j + 4 <= cnt; j += 4){          // 4 sequential rows in flight
    const h16* p0 = base + (size_t)(j+0)*HROW;
    const h16* p1 = base + (size_t)(j+1)*HROW;
    const h16* p2 = base + (size_t)(j+2)*HROW;
    const h16* p3 = base + (size_t)(j+3)*HROW;
    float x0 = (float)p0[t], x1 = (float)p1[t];
    float x2 = (float)p2[t], x3 = (float)p3[t];
    a0 += (x0 + x1) + (x2 + x3);
    if (c1 < EMBD){
      float y0 = (float)p0[c1], y1 = (float)p1[c1];
      float y2 = (float)p2[c1], y3 = (float)p3[c1];
      a1 += (y0 + y1) + (y2 + y3);
    }
  }
  for (; j < cnt; j++){
    const h16* hr = base + (size_t)j*HROW;
    a0 += (float)hr[t];
    if (c1 < EMBD) a1 += (float)hr[c1];
  }
  float inv = 1.0f / fmaxf((float)cnt, 1.0f);
  float v0 = coef[t]*(a0*inv) + coef[HROW + t];
  float v1 = (c1 < EMBD) ? coef[c1]*(a1*inv) + coef[HROW + c1] : 0.f;
  if (mask && mask[g] > 0.5f){
    v0 = memb[t];
    if (c1 < EMBD) v1 = memb[c1];
  }
  float* o = out + (size_t)g*LDF;
  o[t] = v0;
  if (c1 < EMBD) o[c1] = v1;
}
__global__ void k_pool_f32(const float* __restrict__ h, const int* __restrict__ offs,
                           const int* __restrict__ counts, const int* __restrict__ entries,
                           float* __restrict__ out, int M){
  int g = blockIdx.x, t = threadIdx.x, c1 = t + 256;
  int off = offs[g], cnt = counts[g];
  float a0 = 0.f, a1 = 0.f;
  for (int j = 0; j < cnt; j++){
    int r = entries[off + j];
    const float* hr = h + (size_t)r*LDF;
    a0 += hr[t];
    if (c1 < EMBD) a1 += hr[c1];
  }
  float inv = 1.0f / fmaxf((float)cnt, 1.0f);
  float* o = out + (size_t)g*LDF;
  o[t] = a0*inv;
  if (c1 < EMBD) o[c1] = a1*inv;
}

__global__ void k_l2norm(float* __restrict__ f, int M){
  int g = blockIdx.x, t = threadIdx.x, c1 = t + 256;
  float* fr = f + (size_t)g*LDF;
  float v0 = fr[t];
  float v1 = (c1 < EMBD) ? fr[c1] : 0.f;
  float ss = v0*v0 + v1*v1;
  #pragma unroll
  for (int o = 32; o > 0; o >>= 1) ss += __shfl_down(ss, o, 64);
  __shared__ float red[4];
  int wid = t >> 6, lane = t & 63;
  if (lane == 0) red[wid] = ss;
  __syncthreads();
  if (t == 0) red[0] = 1.0f / fmaxf(sqrtf(red[0]+red[1]+red[2]+red[3]), 1e-12f);
  __syncthreads();
  float inv = red[0];
  fr[t] = v0*inv;
  if (c1 < EMBD) fr[c1] = v1*inv;
}

// ---- MFMA fp16 GEMM: C = (A(f32) @ Wp(fp16)^T + adds) * scale ----
// Wp rows are KEXT-stride fp16 with cols >=300 zero.
__global__ void __launch_bounds__(256)
k_gemm16(const float* __restrict__ A, int lda, const h16* __restrict__ Wp,
         const float* __restrict__ bias, const float* __restrict__ e1, const float* __restrict__ e2,
         float* __restrict__ C, int ldc, int M, int Ncols, int relu, float scale)
{
  __shared__ h16 Bs[BCH][BSTR];        // 6.4 KB
  int tid = threadIdx.x;
  int wid = tid >> 6, lane = tid & 63;
  int m16 = lane & 15, ko = lane >> 4;
  int row0 = blockIdx.y * 64;
  int col0 = blockIdx.x * BCH;
  int arow = row0 + wid*16 + m16;
  bool rok = arow < M;
  const float* Ar = A + (size_t)(rok ? arow : 0) * lda;

  half8 afr[10];
  #pragma unroll
  for (int k0 = 0; k0 < 9; k0++){
    const float* p = Ar + k0*32 + ko*8;
    float4 fa = rok ? *(const float4*)p       : (float4){0.f,0.f,0.f,0.f};
    float4 fb = rok ? *(const float4*)(p + 4) : (float4){0.f,0.f,0.f,0.f};
    half8 v;
    v[0]=(h16)fa.x; v[1]=(h16)fa.y; v[2]=(h16)fa.z; v[3]=(h16)fa.w;
    v[4]=(h16)fb.x; v[5]=(h16)fb.y; v[6]=(h16)fb.z; v[7]=(h16)fb.w;
    afr[k0] = v;
  }
  {
    half8 v;
    #pragma unroll
    for (int c = 0; c < 8; c++){
      int ch = 288 + ko*8 + c;
      v[c] = (h16)((rok && ch < EMBD) ? Ar[ch] : 0.f);
    }
    afr[9] = v;
  }

  f32x4 a2[5];
  #pragma unroll
  for (int j = 0; j < 5; j++) a2[j] = (f32x4){0.f,0.f,0.f,0.f};
  for (int k0 = 0; k0 < 10; k0++){
    __syncthreads();
    for (int idx = tid; idx < 320; idx += 256){
      int o = idx >> 2, qd = (idx & 3) * 8;
      *(half8*)&Bs[o][qd] = *(const half8*)(Wp + (size_t)(col0 + o)*KEXT + k0*32 + qd);
    }
    __syncthreads();
    #pragma unroll
    for (int j = 0; j < 5; j++){
      half8 bfr = *(const half8*)&Bs[j*16 + m16][ko*8];
      a2[j] = __builtin_amdgcn_mfma_f32_16x16x32_f16(afr[k0], bfr, a2[j], 0, 0, 0);
    }
  }
  #pragma unroll
  for (int j = 0; j < 5; j++){
    int cc = col0 + j*16 + m16;
    if (cc >= Ncols) continue;
    float add = bias ? (bias[cc] + e1[cc] + e2[cc]) : 0.f;
    #pragma unroll
    for (int r = 0; r < 4; r++){
      int rr = row0 + wid*16 + ko*4 + r;
      if (rr >= M) continue;
      float v = (a2[j][r] + add) * scale;
      if (relu) v = fmaxf(v, 0.f);
      C[(size_t)rr*ldc + cc] = v;
    }
  }
}

// ---------------- host side ----------------
static inline void scan_excl(const int* counts, int M, int* offs, int* bsum, hipStream_t s){
  int B = CE(M, 256);
  k_scan_block<<<B,256,0,s>>>(counts, M, offs, bsum);
  k_scan_sums<<<1,1024,0,s>>>(bsum, B);
  k_scan_add<<<B,256,0,s>>>(offs, bsum, M);
}
static inline void gemm16(const float* A, const h16* Wp,
                          const float* bias, const float* e1, const float* e2,
                          float* C, int M, int relu, hipStream_t s){
  dim3 grid(CE(EMBD, BCH), CE(M, 64));
  k_gemm16<<<grid,256,0,s>>>(A, LDF, Wp, bias, e1, e2, C, LDF, M, EMBD, relu, 1.0f);
}

extern "C" void kernel_launch(void* const* d_in, const int* in_sizes, int n_in,
                              void* d_out, int out_size, void* d_ws, size_t ws_size,
                              hipStream_t stream) {
  const int*   batch_x   = (const int*)d_in[0];
  const int*   batch_ei  = (const int*)d_in[1];
  const int*   batch_ea  = (const int*)d_in[2];
  const int*   batch_gid = (const int*)d_in[3];
  const int*   frag_x    = (const int*)d_in[4];
  const int*   frag_ei   = (const int*)d_in[5];
  const int*   frag_ea   = (const int*)d_in[6];
  const int*   frag_jid  = (const int*)d_in[7];
  const int*   jct_gid   = (const int*)d_in[8];
  const float* jct_mask  = (const float*)d_in[9];
  const float* ae1       = (const float*)d_in[10];
  const float* ae2       = (const float*)d_in[11];
  const float* gnn_W     = (const float*)d_in[12];
  const float* gnn_b     = (const float*)d_in[13];
  const float* gnn_ee1   = (const float*)d_in[14];
  const float* gnn_ee2   = (const float*)d_in[15];
  const float* bn_gamma  = (const float*)d_in[16];
  const float* bn_beta   = (const float*)d_in[17];
  const float* jct_W     = (const float*)d_in[18];
  const float* jct_b     = (const float*)d_in[19];
  const float* jct_ee1   = (const float*)d_in[20];
  const float* jct_ee2   = (const float*)d_in[21];
  const float* mask_emb  = (const float*)d_in[22];

  const int N = in_sizes[0] / 2;       // 200000
  const int E = in_sizes[1] / 2;       // 400000
  const int NG = 1024, NJ = 8192;
  const int LBLK = CE(N, 64);          // fused-layer grid (3125)

  // workspace carve-up (~258 MB)
  size_t off = 0;
  char* base = (char*)d_ws;
  auto carve = [&](size_t bytes) -> void* {
    void* p = base + off;
    off += (bytes + 255) & ~(size_t)255;
    return p;
  };
  h16*  hA      = (h16*) carve((size_t)(N+1) * HROW * 2);   // +1: zero row N
  h16*  hB      = (h16*) carve((size_t)(N+1) * HROW * 2);
  float* dinv    = (float*)carve((size_t)N * 4);
  int*   degcnt  = (int*)  carve((size_t)N * 4);
  int*   cursor  = degcnt;                       // alias: dead after k_dinv
  int*   counts  = (int*)  carve((size_t)N * 4);
  int*   offs    = (int*)  carve((size_t)(N + 1) * 4);
  int*   entries = (int*)  carve((size_t)(E + N) * 4);
  int*   bsum    = (int*)  carve(1024 * 4);
  float* stats   = (float*)carve(2 * EMBD * 4);
  float* coef    = (float*)carve(2 * HROW * 4);
  h16*  coefh   = (h16*) carve(2 * KEXT * 2);
  h16*  wext    = (h16*) carve((size_t)5 * KEXT * KEXT * 2);
  h16*  wjx     = (h16*) carve((size_t)2 * KEXT * KEXT * 2);
  h16*  htabG   = (h16*) carve((size_t)9 * HROW * 2);
  float* ctab    = (float*)carve((size_t)NTAB * HROW * 4);   // layer-0 tables
  unsigned char* pidx = (unsigned char*)carve((size_t)N);
  float* f0      = (float*)carve((size_t)NG * LDF * 4);
  float* f1      = (float*)carve((size_t)NG * LDF * 4);
  h16*  f1h     = (h16*) carve((size_t)1040 * KEXT * 2);    // logits B (fp16, padded)
  int*   pofs    = (int*)  carve((size_t)(NJ + 1) * 4);      // pool CSR
  int*   pcnt    = (int*)  carve((size_t)NJ * 4);
  int*   perm    = (int*)  carve((size_t)N * 4);
  h16*  spart   = (h16*) carve((size_t)LBLK * SPR * 2);     // 3.8 MB BN partials
  size_t required = off;
  // junction-phase fp32 buffers alias hA (dead when used)
  float* g0      = (float*)hA;
  float* t1      = (float*)((char*)hA + ((size_t)16 << 20));
  float* t2      = (float*)((char*)hA + ((size_t)32 << 20));
  (void)n_in;

  if (ws_size < required || d_ws == nullptr){
    float v = 1.0e6f + (float)(ws_size >> 20) * 1000.0f;   // encode ws MB in absmax
    k_diag<<<CE(out_size,256),256,0,stream>>>((float*)d_out, out_size, v);
    return;
  }

  // one-time prep (ctab depends only on weights -> shared by both branches)
  { dim3 g(KEXT, 5); k_wext<<<g,256,0,stream>>>(gnn_W, gnn_b, gnn_ee1, gnn_ee2, wext); }
  { dim3 g(KEXT, 2); k_wpad<<<g,256,0,stream>>>(jct_W, wjx); }
  k_htab<<<9,256,0,stream>>>(ae1, ae2, htabG);
  k_ctab<<<NTAB,256,0,stream>>>(htabG, wext, ctab);
  hipMemsetAsync(stats, 0, 2*EMBD*4, stream);              // k_bn_coef re-zeros after use
  hipMemsetAsync(hA + (size_t)N*HROW, 0, HROW*2, stream);
  hipMemsetAsync(hB + (size_t)N*HROW, 0, HROW*2, stream);

  for (int br = 0; br < 2; br++){
    const int* x   = br ? frag_x   : batch_x;
    const int* ei  = br ? frag_ei  : batch_ei;
    const int* ea  = br ? frag_ea  : batch_ea;
    const int* gid = br ? frag_jid : batch_gid;
    const int  M   = br ? NJ       : NG;

    // degree (src) + dst-counts in ONE edge pass; then dinv + CSR
    k_init_deg<<<CE(N,256),256,0,stream>>>(degcnt, counts, N);
    k_count_both<<<CE(E,256),256,0,stream>>>(ei, E, degcnt, counts);
    k_dinv<<<CE(N,256),256,0,stream>>>(degcnt, dinv, N);
    scan_excl(counts, N, offs, bsum, stream);
    hipMemsetAsync(cursor, 0, (size_t)N*4, stream);
    k_fill_edges<<<CE(E+N,256),256,0,stream>>>(ei, ea, E, N, offs, cursor, entries);
    k_pidx<<<CE(N,256),256,0,stream>>>(x, pidx, N);

    // pool CSR + permutation (layer 4 writes pool-sorted)
    hipMemsetAsync(pcnt, 0, (size_t)M*4, stream);
    k_count_ids<<<CE(N,256),256,0,stream>>>(gid, N, pcnt);
    scan_excl(pcnt, M, pofs, bsum, stream);
    hipMemsetAsync(cursor, 0, (size_t)M*4, stream);
    k_fill_perm<<<CE(N,256),256,0,stream>>>(gid, N, pofs, cursor, perm);

    // 5 fused layers; layer 0 = 24-table form; layer 4 writes permuted
    for (int l = 0; l < 5; l++){
      const h16* src = (l & 1) ? hB : hA;
      h16*       dst = (l & 1) ? hA : hB;
      if (l == 0)
        k_layer0<<<LBLK,256,0,stream>>>(pidx, ctab, dinv, offs, counts, entries,
                                        hB, N, spart);
      else
        k_layer<1><<<LBLK,256,0,stream>>>(src, coefh, dinv, offs, counts, entries,
                                          wext + (size_t)l*KEXT*KEXT, dst, N, spart,
                                          (l == 4) ? perm : nullptr);
      k_red_stats<<<64,256,0,stream>>>(spart, LBLK, stats);
      k_bn_coef<<<CE(KEXT,256),256,0,stream>>>(stats, bn_gamma + l*EMBD, bn_beta + l*EMBD,
                                               coef, coefh, 1.0f/(float)N);
    }
    // hB holds PERMUTED raw layer-4 output; BN affine fused into the pool.

    if (br == 0){
      k_pool_h<<<NG,256,0,stream>>>(hB, pofs, pcnt, g0, coef, nullptr, nullptr);
      gemm16(g0, wjx,
             jct_b, jct_ee1 + 4*EMBD, jct_ee2, t1, NG, 1, stream);
      gemm16(t1, wjx + (size_t)KEXT*KEXT,
             jct_b + EMBD, jct_ee1 + 6*EMBD + 4*EMBD, jct_ee2 + 3*EMBD, f0, NG, 0, stream);
      k_l2norm<<<NG,256,0,stream>>>(f0, NG);
    } else {
      k_pool_h<<<NJ,256,0,stream>>>(hB, pofs, pcnt, t1, coef, jct_mask, mask_emb);
      gemm16(t1, wjx,
             jct_b, jct_ee1 + 4*EMBD, jct_ee2, t2, NJ, 1, stream);
      gemm16(t2, wjx + (size_t)KEXT*KEXT,
             jct_b + EMBD, jct_ee1 + 6*EMBD + 4*EMBD, jct_ee2 + 3*EMBD, t1, NJ, 0, stream);
      // junction -> graph pool (small; entries-based)
      hipMemsetAsync(counts, 0, (size_t)NG*4, stream);
      k_count_ids<<<CE(NJ,256),256,0,stream>>>(jct_gid, NJ, counts);
      scan_excl(counts, NG, offs, bsum, stream);
      hipMemsetAsync(cursor, 0, (size_t)NG*4, stream);
      k_fill_rows<<<CE(NJ,256),256,0,stream>>>(jct_gid, NJ, offs, cursor, entries);
      k_pool_f32<<<NG,256,0,stream>>>(t1, offs, counts, entries, f1, NG);
      k_l2norm<<<NG,256,0,stream>>>(f1, NG);
    }
  }

  // logits = (f0 @ f1^T) / TEMP via MFMA fp16 (f1 -> padded fp16 B-matrix)
  k_f16rows<<<1040,256,0,stream>>>(f1, NG, f1h);
  {
    dim3 grid(CE(NG, BCH), CE(NG, 64));
    k_gemm16<<<grid,256,0,stream>>>(f0, LDF, f1h, nullptr, nullptr, nullptr,
                                    (float*)d_out, 1024, NG, NG, 0, 25.0f);
  }
}

// Round 9
// 3458.568 us; speedup vs baseline: 1.0004x; 1.0004x over previous
//
#include <hip/hip_runtime.h>
#include <math.h>

#define EMBD 300
#define HROW 304     // fp16 h row stride (elements) = 608 B; cols 300-303 = 0
#define LDF  304     // fp32 junction-phase row stride
#define KEXT 320     // extended K: 304 h(+pad) + 1 bias + 6 ee1 + 3 ee2 + 6 pad
#define BCH  80      // B cols per jt chunk (4 chunks of 80 = 320)
#define BSTR 40      // LDS B row stride (halves): 80 B
#define TS2  312     // LDS C-tile row stride (halves): 624 B
#define SPR  608     // spart row stride (halves): [0..299]=sum, [304..603]=sumsq
#define NTAB 24      // layer-0 tables: 9 htab@Wx^T + 15 ext (bt 0..4 x bd 0..2)
#define CE(a,b) (((a)+(b)-1)/(b))

typedef _Float16 h16;
typedef __attribute__((ext_vector_type(8))) _Float16 half8;
typedef __attribute__((ext_vector_type(4))) float f32x4;

// ---------------- utility / CSR kernels ----------------
__global__ void k_diag(float* out, int n, float v){
  int i = blockIdx.x*256 + threadIdx.x;
  if (i < n) out[i] = v;
}
// degcnt = 0, counts = 1 (self-loop) in one pass
__global__ void k_init_deg(int* __restrict__ deg, int* __restrict__ cnts, int N){
  int i = blockIdx.x*256 + threadIdx.x;
  if (i < N){ deg[i] = 0; cnts[i] = 1; }
}
// one pass over edges: src-degree (for dinv) + dst-counts (for CSR)
__global__ void k_count_both(const int* __restrict__ ei, int E,
                             int* __restrict__ deg, int* __restrict__ cnts){
  int e = blockIdx.x*256 + threadIdx.x;
  if (e < E){
    atomicAdd(&deg[ei[e]], 1);
    atomicAdd(&cnts[ei[E + e]], 1);
  }
}
__global__ void k_dinv(const int* __restrict__ deg, float* __restrict__ dinv, int N){
  int i = blockIdx.x*256 + threadIdx.x;
  if (i < N) dinv[i] = 1.0f / sqrtf((float)(deg[i] + 1));   // +1 self-loop
}
__global__ void k_count_ids(const int* __restrict__ ids, int n, int* __restrict__ counts){
  int i = blockIdx.x*256 + threadIdx.x;
  if (i < n) atomicAdd(&counts[ids[i]], 1);
}
__global__ void k_scan_block(const int* __restrict__ in, int M, int* __restrict__ out, int* __restrict__ bsum){
  __shared__ int s[256];
  int t = threadIdx.x, i = blockIdx.x*256 + t;
  int v = (i < M) ? in[i] : 0;
  s[t] = v; __syncthreads();
  for (int off = 1; off < 256; off <<= 1){
    int x = (t >= off) ? s[t-off] : 0;
    __syncthreads();
    s[t] += x;
    __syncthreads();
  }
  if (i < M) out[i] = s[t] - v;
  if (t == 255) bsum[blockIdx.x] = s[255];
}
__global__ void k_scan_sums(int* __restrict__ bsum, int B){   // B <= 1024
  __shared__ int s[1024];
  int t = threadIdx.x;
  int v = (t < B) ? bsum[t] : 0;
  s[t] = v; __syncthreads();
  for (int off = 1; off < 1024; off <<= 1){
    int x = (t >= off) ? s[t-off] : 0;
    __syncthreads();
    s[t] += x;
    __syncthreads();
  }
  if (t < B) bsum[t] = s[t] - v;
}
__global__ void k_scan_add(int* __restrict__ out, const int* __restrict__ bsum, int M){
  int i = blockIdx.x*256 + threadIdx.x;
  if (i < M) out[i] += bsum[blockIdx.x];
}
// entries payload: src | bt<<20 | bd<<23   (src < 2^20)
__global__ void k_fill_edges(const int* __restrict__ ei, const int* __restrict__ ea, int E, int N,
                             const int* __restrict__ offs, int* __restrict__ cur, int* __restrict__ entries){
  int e = blockIdx.x*256 + threadIdx.x;
  if (e < E){
    int s  = ei[e];
    int d  = ei[E + e];
    int bt = ea[2*e], bd = ea[2*e + 1];
    int pos = offs[d] + atomicAdd(&cur[d], 1);
    entries[pos] = s | (bt << 20) | (bd << 23);
  } else if (e < E + N){
    int i = e - E;                          // self-loop: bond type 4, dir 0
    int pos = offs[i] + atomicAdd(&cur[i], 1);
    entries[pos] = i | (4 << 20);
  }
}
__global__ void k_fill_rows(const int* __restrict__ ids, int n, const int* __restrict__ offs,
                            int* __restrict__ cur, int* __restrict__ entries){
  int i = blockIdx.x*256 + threadIdx.x;
  if (i < n){
    int g = ids[i];
    int pos = offs[g] + atomicAdd(&cur[g], 1);
    entries[pos] = i;
  }
}
// pool permutation: node i -> slot perm[i] (slots of a graph are contiguous)
__global__ void k_fill_perm(const int* __restrict__ ids, int n, const int* __restrict__ offs,
                            int* __restrict__ cur, int* __restrict__ perm){
  int i = blockIdx.x*256 + threadIdx.x;
  if (i < n){
    int g = ids[i];
    perm[i] = offs[g] + atomicAdd(&cur[g], 1);
  }
}

// ---------------- model kernels ----------------
// h0 has only 9 distinct rows (x entries are in [0,3)): htab[p] = ae1[p/3]+ae2[p%3]
__global__ void k_htab(const float* __restrict__ ae1, const float* __restrict__ ae2,
                       h16* __restrict__ htab){
  int p = blockIdx.x;                 // 0..8
  int a = p / 3, b = p % 3;
  int t = threadIdx.x;
  h16* d = htab + (size_t)p*HROW;
  for (int c = t; c < HROW; c += 256)
    d[c] = (c < EMBD) ? (h16)(ae1[(size_t)a*EMBD + c] + ae2[(size_t)b*EMBD + c]) : (h16)0.f;
}
__global__ void k_pidx(const int* __restrict__ x, unsigned char* __restrict__ pidx, int N){
  int i = blockIdx.x*256 + threadIdx.x;
  if (i < N) pidx[i] = (unsigned char)(x[2*i]*3 + x[2*i+1]);
}
// layer-0 tables: ctab[q][o].  q<9: htab[q] @ Wx[o]^T (fp16 ops, f32 accum).
// q>=9: Wx[o][304] + Wx[o][305+bt] + Wx[o][311+bd].
__global__ void k_ctab(const h16* __restrict__ htabG, const h16* __restrict__ Wx,
                       float* __restrict__ ctab){
  int q = blockIdx.x, t = threadIdx.x;
  float* d = ctab + (size_t)q*HROW;
  if (q < 9){
    const h16* hr = htabG + (size_t)q*HROW;
    for (int o = t; o < HROW; o += 256){
      float s = 0.f;
      if (o < EMBD){
        const h16* wr = Wx + (size_t)o*KEXT;
        for (int k = 0; k < EMBD; k++)
          s += (float)hr[k] * (float)wr[k];
      }
      d[o] = s;
    }
  } else {
    int bt = (q - 9) / 3, bd = (q - 9) % 3;
    for (int o = t; o < HROW; o += 256){
      float s = 0.f;
      if (o < EMBD){
        const h16* wr = Wx + (size_t)o*KEXT;
        s = (float)wr[304] + (float)wr[305 + bt] + (float)wr[311 + bd];
      }
      d[o] = s;
    }
  }
}

// extended weights (fp16): Wx[l][o][k], o,k in [0,KEXT)
// k<300: W[o][k]; k==304: b[o]; 305..310: ee1; 311..313: ee2; else 0
__global__ void k_wext(const float* __restrict__ W, const float* __restrict__ b,
                       const float* __restrict__ ee1, const float* __restrict__ ee2,
                       h16* __restrict__ out){
  int l = blockIdx.y, o = blockIdx.x, t = threadIdx.x;
  h16* d = out + ((size_t)l*KEXT + o)*KEXT;
  for (int k = t; k < KEXT; k += 256){
    float v = 0.f;
    if (o < EMBD){
      if      (k < EMBD)            v = W[(size_t)l*EMBD*EMBD + (size_t)o*EMBD + k];
      else if (k == 304)            v = b[l*EMBD + o];
      else if (k >= 305 && k < 311) v = ee1[((size_t)l*6 + (k-305))*EMBD + o];
      else if (k >= 311 && k < 314) v = ee2[((size_t)l*3 + (k-311))*EMBD + o];
    }
    d[k] = (h16)v;
  }
}
// plain fp16 zero-pad of jct_W: wjx[l][o][k], 320x320, grid (KEXT, 2)
__global__ void k_wpad(const float* __restrict__ W, h16* __restrict__ out){
  int l = blockIdx.y, o = blockIdx.x, t = threadIdx.x;
  h16* d = out + ((size_t)l*KEXT + o)*KEXT;
  for (int k = t; k < KEXT; k += 256)
    d[k] = (h16)((o < EMBD && k < EMBD) ? W[(size_t)l*EMBD*EMBD + (size_t)o*EMBD + k] : 0.f);
}
// f32 rows [M][LDF] -> fp16 rows [Mpad][KEXT] (zero-padded), for MFMA B operand
__global__ void k_f16rows(const float* __restrict__ src, int M, h16* __restrict__ dst){
  int r = blockIdx.x, t = threadIdx.x;
  h16* d = dst + (size_t)r*KEXT;
  for (int k = t; k < KEXT; k += 256)
    d[k] = (h16)((r < M && k < EMBD) ? src[(size_t)r*LDF + k] : 0.f);
}

// BN affine from stats: fp32 (for pooled rows) + fp16 (for gather).
// Also RE-ZEROS stats for the next layer (drops the per-layer memset).
__global__ void k_bn_coef(float* __restrict__ stats, const float* __restrict__ gamma,
                          const float* __restrict__ beta, float* __restrict__ coef,
                          h16* __restrict__ coefh, float invN){
  int c = blockIdx.x*256 + threadIdx.x;
  if (c >= KEXT) return;
  float sc = 0.f, sh = 0.f;
  if (c < EMBD){
    float mu  = stats[c]*invN;
    float var = stats[EMBD + c]*invN - mu*mu;
    sc = gamma[c]*rsqrtf(var + 1e-5f);
    sh = beta[c] - mu*sc;
    stats[c] = 0.f; stats[EMBD + c] = 0.f;
  }
  if (c < HROW){ coef[c] = sc; coef[HROW + c] = sh; }
  coefh[c] = (h16)sc; coefh[KEXT + c] = (h16)sh;
}

// reduce per-block fp16 stat partials -> stats[600] (f32)
__global__ void k_red_stats(const h16* __restrict__ spart, int nb, float* __restrict__ stats){
  int t = threadIdx.x;
  int c1 = t + 256;                      // valid only for t < 44
  float a0 = 0.f, q0 = 0.f, a1 = 0.f, q1 = 0.f;
  for (int b = blockIdx.x; b < nb; b += gridDim.x){
    const h16* sp = spart + (size_t)b*SPR;
    a0 += (float)sp[t];
    q0 += (float)sp[304 + t];
    if (c1 < EMBD){ a1 += (float)sp[c1]; q1 += (float)sp[304 + c1]; }
  }
  if (t < EMBD){ atomicAdd(&stats[t], a0); atomicAdd(&stats[EMBD + t], q0); }
  if (c1 < EMBD){ atomicAdd(&stats[c1], a1); atomicAdd(&stats[EMBD + c1], q1); }
}

// ---- fused layer (layers 1-4): fixed-8 fan-out gather -> MFMA -> BN stats ----
// PERM is a compile-time switch: PERM=0 keeps the round-7 codegen (no LDS
// indirection in the writeout; r8 post-mortem: the runtime branch cost ~29 us
// on EVERY layer). PERM=1 (layer 4 only) writes pool-sorted rows.
template<int RELU, int PERM>
__global__ void __launch_bounds__(256)
k_layer(const h16* __restrict__ hRaw, const h16* __restrict__ coefh,
        const float* __restrict__ dinv,
        const int* __restrict__ offs, const int* __restrict__ counts,
        const int* __restrict__ entries, const h16* __restrict__ Wx,
        h16* __restrict__ hOut, int N, h16* __restrict__ spart,
        const int* __restrict__ perm)
{
  __shared__ h16  tile[64][TS2];       // 39.9 KB persistent C tile
  __shared__ h16  Bs[BCH][BSTR];       //  6.4 KB B chunk (80 cols x 32 k)
  __shared__ float sred[2*HROW];       //  2.4 KB BN partials
  __shared__ int   rstart[64];
  __shared__ int   rcnt[64];
  __shared__ int   prow[PERM ? 64 : 1];
  __shared__ float dvv[64];

  int tid = threadIdx.x;
  int wid = tid >> 6, lane = tid & 63;
  int m16 = lane & 15, ko = lane >> 4;
  long row0 = (long)blockIdx.x * 64;

  if (tid < 64){
    long g = row0 + tid;
    int o = 0, c = 0; float d = 0.f;
    if (g < N){ o = offs[g]; c = counts[g]; d = dinv[g]; }
    rstart[tid] = o; rcnt[tid] = c; dvv[tid] = d;
    if (PERM) prow[PERM ? tid : 0] = (g < N) ? perm[g] : (int)g;
  }
  for (int i = tid; i < 2*HROW; i += 256) sred[i] = 0.f;
  __syncthreads();

  int lr = wid*16 + m16;
  int myStart = rstart[lr], myCnt = rcnt[lr];
  float di = dvv[lr];

  // ---- prefetch up to 8 edge descriptors + weights ----
  int srcA[8]; float wvA[8]; int eA[8];
  #pragma unroll
  for (int j = 0; j < 8; j++){
    int e = entries[myStart + j];               // bounded over-read ok (within ws)
    bool act = j < myCnt;
    int s = act ? (e & 0xFFFFF) : N;            // row N is all-zero
    float wv = dinv[act ? s : 0];
    wvA[j] = act ? wv : 0.f;
    srcA[j] = s; eA[j] = e;
  }
  float ext[8] = {0,0,0,0,0,0,0,0};
  if (ko >= 2){
    int extbase = (ko - 2)*8;
    #pragma unroll
    for (int j = 0; j < 8; j++){
      unsigned msk = 1u | (1u << (1 + ((eA[j] >> 20) & 7))) | (1u << (7 + ((eA[j] >> 23) & 3)));
      #pragma unroll
      for (int c = 0; c < 8; c++)
        ext[c] += ((msk >> (extbase + c)) & 1u) ? wvA[j] : 0.f;
    }
  }
  half8 wvh[8];
  #pragma unroll
  for (int j = 0; j < 8; j++){
    _Float16 w = (_Float16)wvA[j];
    #pragma unroll
    for (int c = 0; c < 8; c++) wvh[j][c] = w;
  }

  half8 acc[10];
  #pragma unroll
  for (int k = 0; k < 10; k++) acc[k] = (half8)(_Float16)0;

  // ---- rare overflow: rows with cnt > 8 (per-lane divergent) ----
  if (__any(myCnt > 8)){
    for (int j = 8; j < myCnt; j++){
      int e = entries[myStart + j];
      int s = e & 0xFFFFF;
      float wv = dinv[s];
      if (ko >= 2){
        int extbase = (ko - 2)*8;
        unsigned msk = 1u | (1u << (1 + ((e >> 20) & 7))) | (1u << (7 + ((e >> 23) & 3)));
        #pragma unroll
        for (int c = 0; c < 8; c++)
          ext[c] += ((msk >> (extbase + c)) & 1u) ? wv : 0.f;
      }
      _Float16 wh = (_Float16)wv;
      half8 w8;
      #pragma unroll
      for (int c = 0; c < 8; c++) w8[c] = wh;
      #pragma unroll
      for (int k = 0; k < 10; k++){
        if (k == 9 && ko >= 2) break;
        half8 sck = *(const half8*)&coefh[k*32 + ko*8];
        half8 shk = *(const half8*)&coefh[KEXT + k*32 + ko*8];
        half8 x = *(const half8*)(hRaw + (size_t)s*HROW + k*32 + ko*8);
        half8 y = sck*x + shk;
        if (RELU){
          #pragma unroll
          for (int c = 0; c < 8; c++) y[c] = y[c] > (_Float16)0 ? y[c] : (_Float16)0;
        }
        acc[k] += w8*y;
      }
    }
  }

  // ---- main gather: chunk-outer, fixed 8 edges inner (8 loads in flight) ----
  #pragma unroll
  for (int k = 0; k < 9; k++){
    half8 sck = *(const half8*)&coefh[k*32 + ko*8];
    half8 shk = *(const half8*)&coefh[KEXT + k*32 + ko*8];
    half8 a = acc[k];
    #pragma unroll
    for (int j = 0; j < 8; j++){
      half8 x = *(const half8*)(hRaw + (size_t)srcA[j]*HROW + k*32 + ko*8);
      half8 y = sck*x + shk;
      if (RELU){
        #pragma unroll
        for (int c = 0; c < 8; c++) y[c] = y[c] > (_Float16)0 ? y[c] : (_Float16)0;
      }
      a += wvh[j]*y;
    }
    acc[k] = a;
  }
  { // k = 9: ko<2 covers cols 288-303 (coef 300-303 = 0); ko>=2 = ext scalars
    half8 a = acc[9];
    if (ko < 2){
      half8 sck = *(const half8*)&coefh[288 + ko*8];
      half8 shk = *(const half8*)&coefh[KEXT + 288 + ko*8];
      #pragma unroll
      for (int j = 0; j < 8; j++){
        half8 x = *(const half8*)(hRaw + (size_t)srcA[j]*HROW + 288 + ko*8);
        half8 y = sck*x + shk;
        if (RELU){
          #pragma unroll
          for (int c = 0; c < 8; c++) y[c] = y[c] > (_Float16)0 ? y[c] : (_Float16)0;
        }
        a += wvh[j]*y;
      }
    } else {
      #pragma unroll
      for (int c = 0; c < 8; c++) a[c] += (_Float16)ext[c];
    }
    acc[9] = a;
  }

  // scale by dinv[dst]
  half8 afr[10];
  {
    _Float16 dh = (_Float16)di;
    half8 d8;
    #pragma unroll
    for (int c = 0; c < 8; c++) d8[c] = dh;
    #pragma unroll
    for (int k = 0; k < 10; k++) afr[k] = acc[k] * d8;
  }

  // ---- GEMM over 4 col-chunks of 80; C staged to persistent LDS tile ----
  int cr = ko * 4;
  #pragma unroll
  for (int jt = 0; jt < 4; jt++){
    f32x4 a2[5];
    #pragma unroll
    for (int j = 0; j < 5; j++) a2[j] = (f32x4){0.f,0.f,0.f,0.f};
    for (int k0 = 0; k0 < 10; k0++){
      __syncthreads();
      for (int idx = tid; idx < 320; idx += 256){
        int o = idx >> 2, qd = (idx & 3) * 8;
        *(half8*)&Bs[o][qd] = *(const half8*)(Wx + (size_t)(jt*BCH + o)*KEXT + k0*32 + qd);
      }
      __syncthreads();
      #pragma unroll
      for (int j = 0; j < 5; j++){
        half8 bfr = *(const half8*)&Bs[j*16 + m16][ko*8];
        a2[j] = __builtin_amdgcn_mfma_f32_16x16x32_f16(afr[k0], bfr, a2[j], 0, 0, 0);
      }
    }
    // BN partials from registers (LDS atomics only)
    #pragma unroll
    for (int j = 0; j < 5; j++){
      int col = jt*BCH + j*16 + m16;
      float s = 0.f, q = 0.f;
      #pragma unroll
      for (int r = 0; r < 4; r++){
        float v = a2[j][r];
        s += v; q += v*v;
      }
      s += __shfl_xor(s, 16, 64); s += __shfl_xor(s, 32, 64);
      q += __shfl_xor(q, 16, 64); q += __shfl_xor(q, 32, 64);
      if (ko == 0 && col < EMBD){
        atomicAdd(&sred[col], s);
        atomicAdd(&sred[HROW + col], q);
      }
    }
    // stage to tile (wave-private rows: no barrier needed)
    #pragma unroll
    for (int j = 0; j < 5; j++){
      int col = jt*BCH + j*16 + m16;
      if (col < HROW){
        #pragma unroll
        for (int r = 0; r < 4; r++)
          tile[wid*16 + cr + r][col] = (h16)a2[j][r];
      }
    }
  }
  __syncthreads();
  // ---- coalesced writeout: full 608 B rows, each line written once ----
  for (int idx = tid; idx < 64*38; idx += 256){
    int row = idx / 38, c = idx - row*38;
    long grow = row0 + row;
    if (grow < N){
      size_t rbase = PERM ? (size_t)prow[PERM ? row : 0] : (size_t)grow;
      *(uint4*)(hOut + rbase*HROW + c*8) = *(const uint4*)&tile[row][c*8];
    }
  }
  // ---- BN partials -> per-block fp16 slab (no global atomics) ----
  h16* sp = spart + (size_t)blockIdx.x*SPR;
  for (int c = tid; c < EMBD; c += 256){
    sp[c]       = (h16)sred[c];
    sp[304 + c] = (h16)sred[HROW + c];
  }
}

// ---- layer 0, table form: out[d] = dinv[d] * sum_q coef_q(d) * ctab[q] ----
__global__ void __launch_bounds__(256)
k_layer0(const unsigned char* __restrict__ pidx, const float* __restrict__ ctab,
         const float* __restrict__ dinv,
         const int* __restrict__ offs, const int* __restrict__ counts,
         const int* __restrict__ entries,
         h16* __restrict__ hOut, int N, h16* __restrict__ spart)
{
  __shared__ float tabs[NTAB][HROW];   // 29.2 KB
  __shared__ float cf[64][NTAB];       //  6.0 KB
  __shared__ float sred[2*HROW];       //  2.4 KB
  int tid = threadIdx.x;
  long row0 = (long)blockIdx.x * 64;

  for (int i = tid; i < NTAB*HROW; i += 256) ((float*)tabs)[i] = ctab[i];
  for (int i = tid; i < 64*NTAB; i += 256) ((float*)cf)[i] = 0.f;
  for (int i = tid; i < 2*HROW; i += 256) sred[i] = 0.f;
  __syncthreads();

  if (tid < 64){
    long g = row0 + tid;
    if (g < N){
      int o = offs[g], c = counts[g];
      float dv = dinv[g];
      float* cr = cf[tid];
      for (int j = 0; j < c; j++){
        int e = entries[o + j];
        int s = e & 0xFFFFF;
        int bt = (e >> 20) & 7, bd = (e >> 23) & 3;
        float wv = dinv[s];
        cr[pidx[s]] += wv;
        cr[9 + bt*3 + bd] += wv;
      }
      #pragma unroll
      for (int q = 0; q < NTAB; q++) cr[q] *= dv;   // fold dinv[dst]
    }
  }
  __syncthreads();

  // output: work item w = (row-group rg of 8 rows) x (16B col-chunk c of 38)
  for (int w = tid; w < 8*38; w += 256){
    int c = w % 38, rg = w / 38;
    float v[8][8];
    #pragma unroll
    for (int r = 0; r < 8; r++)
      #pragma unroll
      for (int cc = 0; cc < 8; cc++) v[r][cc] = 0.f;
    for (int q = 0; q < NTAB; q++){
      float tr[8];
      #pragma unroll
      for (int cc = 0; cc < 8; cc++) tr[cc] = tabs[q][c*8 + cc];
      #pragma unroll
      for (int r = 0; r < 8; r++){
        float co = cf[rg*8 + r][q];
        #pragma unroll
        for (int cc = 0; cc < 8; cc++) v[r][cc] += co * tr[cc];
      }
    }
    float s[8], qq[8];
    #pragma unroll
    for (int cc = 0; cc < 8; cc++){ s[cc] = 0.f; qq[cc] = 0.f; }
    #pragma unroll
    for (int r = 0; r < 8; r++){
      long grow = row0 + rg*8 + r;
      if (grow < N){
        half8 hv;
        #pragma unroll
        for (int cc = 0; cc < 8; cc++){
          float x = v[r][cc];
          hv[cc] = (h16)x;
          s[cc] += x; qq[cc] += x*x;
        }
        *(half8*)(hOut + grow*HROW + c*8) = hv;
      }
    }
    #pragma unroll
    for (int cc = 0; cc < 8; cc++){
      atomicAdd(&sred[c*8 + cc], s[cc]);
      atomicAdd(&sred[HROW + c*8 + cc], qq[cc]);
    }
  }
  __syncthreads();
  h16* sp = spart + (size_t)blockIdx.x*SPR;
  for (int c = tid; c < EMBD; c += 256){
    sp[c]       = (h16)sred[c];
    sp[304 + c] = (h16)sred[HROW + c];
  }
}

// mean-pool over CONTIGUOUS permuted rows + fused BN affine (+ optional mask)
__global__ void k_pool_h(const h16* __restrict__ h, const int* __restrict__ offs,
                         const int* __restrict__ counts,
                         float* __restrict__ out, const float* __restrict__ coef,
                         const float* __restrict__ mask, const float* __restrict__ memb){
  int g = blockIdx.x, t = threadIdx.x, c1 = t + 256;
  int off = offs[g], cnt = counts[g];
  float a0 = 0.f, a1 = 0.f;
  const h16* base = h + (size_t)off*HROW;
  int j = 0;
  for (; j + 4 <= cnt; j += 4){          // 4 sequential rows in flight
    const h16* p0 = base + (size_t)(j+0)*HROW;
    const h16* p1 = base + (size_t)(j+1)*HROW;
    const h16* p2 = base + (size_t)(j+2)*HROW;
    const h16* p3 = base + (size_t)(j+3)*HROW;
    float x0 = (float)p0[t], x1 = (float)p1[t];
    float x2 = (float)p2[t], x3 = (float)p3[t];
    a0 += (x0 + x1) + (x2 + x3);
    if (c1 < EMBD){
      float y0 = (float)p0[c1], y1 = (float)p1[c1];
      float y2 = (float)p2[c1], y3 = (float)p3[c1];
      a1 += (y0 + y1) + (y2 + y3);
    }
  }
  for (; j < cnt; j++){
    const h16* hr = base + (size_t)j*HROW;
    a0 += (float)hr[t];
    if (c1 < EMBD) a1 += (float)hr[c1];
  }
  float inv = 1.0f / fmaxf((float)cnt, 1.0f);
  float v0 = coef[t]*(a0*inv) + coef[HROW + t];
  float v1 = (c1 < EMBD) ? coef[c1]*(a1*inv) + coef[HROW + c1] : 0.f;
  if (mask && mask[g] > 0.5f){
    v0 = memb[t];
    if (c1 < EMBD) v1 = memb[c1];
  }
  float* o = out + (size_t)g*LDF;
  o[t] = v0;
  if (c1 < EMBD) o[c1] = v1;
}
__global__ void k_pool_f32(const float* __restrict__ h, const int* __restrict__ offs,
                           const int* __restrict__ counts, const int* __restrict__ entries,
                           float* __restrict__ out, int M){
  int g = blockIdx.x, t = threadIdx.x, c1 = t + 256;
  int off = offs[g], cnt = counts[g];
  float a0 = 0.f, a1 = 0.f;
  for (int j = 0; j < cnt; j++){
    int r = entries[off + j];
    const float* hr = h + (size_t)r*LDF;
    a0 += hr[t];
    if (c1 < EMBD) a1 += hr[c1];
  }
  float inv = 1.0f / fmaxf((float)cnt, 1.0f);
  float* o = out + (size_t)g*LDF;
  o[t] = a0*inv;
  if (c1 < EMBD) o[c1] = a1*inv;
}

__global__ void k_l2norm(float* __restrict__ f, int M){
  int g = blockIdx.x, t = threadIdx.x, c1 = t + 256;
  float* fr = f + (size_t)g*LDF;
  float v0 = fr[t];
  float v1 = (c1 < EMBD) ? fr[c1] : 0.f;
  float ss = v0*v0 + v1*v1;
  #pragma unroll
  for (int o = 32; o > 0; o >>= 1) ss += __shfl_down(ss, o, 64);
  __shared__ float red[4];
  int wid = t >> 6, lane = t & 63;
  if (lane == 0) red[wid] = ss;
  __syncthreads();
  if (t == 0) red[0] = 1.0f / fmaxf(sqrtf(red[0]+red[1]+red[2]+red[3]), 1e-12f);
  __syncthreads();
  float inv = red[0];
  fr[t] = v0*inv;
  if (c1 < EMBD) fr[c1] = v1*inv;
}

// ---- MFMA fp16 GEMM: C = (A(f32) @ Wp(fp16)^T + adds) * scale ----
// Wp rows are KEXT-stride fp16 with cols >=300 zero.
__global__ void __launch_bounds__(256)
k_gemm16(const float* __restrict__ A, int lda, const h16* __restrict__ Wp,
         const float* __restrict__ bias, const float* __restrict__ e1, const float* __restrict__ e2,
         float* __restrict__ C, int ldc, int M, int Ncols, int relu, float scale)
{
  __shared__ h16 Bs[BCH][BSTR];        // 6.4 KB
  int tid = threadIdx.x;
  int wid = tid >> 6, lane = tid & 63;
  int m16 = lane & 15, ko = lane >> 4;
  int row0 = blockIdx.y * 64;
  int col0 = blockIdx.x * BCH;
  int arow = row0 + wid*16 + m16;
  bool rok = arow < M;
  const float* Ar = A + (size_t)(rok ? arow : 0) * lda;

  half8 afr[10];
  #pragma unroll
  for (int k0 = 0; k0 < 9; k0++){
    const float* p = Ar + k0*32 + ko*8;
    float4 fa = rok ? *(const float4*)p       : (float4){0.f,0.f,0.f,0.f};
    float4 fb = rok ? *(const float4*)(p + 4) : (float4){0.f,0.f,0.f,0.f};
    half8 v;
    v[0]=(h16)fa.x; v[1]=(h16)fa.y; v[2]=(h16)fa.z; v[3]=(h16)fa.w;
    v[4]=(h16)fb.x; v[5]=(h16)fb.y; v[6]=(h16)fb.z; v[7]=(h16)fb.w;
    afr[k0] = v;
  }
  {
    half8 v;
    #pragma unroll
    for (int c = 0; c < 8; c++){
      int ch = 288 + ko*8 + c;
      v[c] = (h16)((rok && ch < EMBD) ? Ar[ch] : 0.f);
    }
    afr[9] = v;
  }

  f32x4 a2[5];
  #pragma unroll
  for (int j = 0; j < 5; j++) a2[j] = (f32x4){0.f,0.f,0.f,0.f};
  for (int k0 = 0; k0 < 10; k0++){
    __syncthreads();
    for (int idx = tid; idx < 320; idx += 256){
      int o = idx >> 2, qd = (idx & 3) * 8;
      *(half8*)&Bs[o][qd] = *(const half8*)(Wp + (size_t)(col0 + o)*KEXT + k0*32 + qd);
    }
    __syncthreads();
    #pragma unroll
    for (int j = 0; j < 5; j++){
      half8 bfr = *(const half8*)&Bs[j*16 + m16][ko*8];
      a2[j] = __builtin_amdgcn_mfma_f32_16x16x32_f16(afr[k0], bfr, a2[j], 0, 0, 0);
    }
  }
  #pragma unroll
  for (int j = 0; j < 5; j++){
    int cc = col0 + j*16 + m16;
    if (cc >= Ncols) continue;
    float add = bias ? (bias[cc] + e1[cc] + e2[cc]) : 0.f;
    #pragma unroll
    for (int r = 0; r < 4; r++){
      int rr = row0 + wid*16 + ko*4 + r;
      if (rr >= M) continue;
      float v = (a2[j][r] + add) * scale;
      if (relu) v = fmaxf(v, 0.f);
      C[(size_t)rr*ldc + cc] = v;
    }
  }
}

// ---------------- host side ----------------
static inline void scan_excl(const int* counts, int M, int* offs, int* bsum, hipStream_t s){
  int B = CE(M, 256);
  k_scan_block<<<B,256,0,s>>>(counts, M, offs, bsum);
  k_scan_sums<<<1,1024,0,s>>>(bsum, B);
  k_scan_add<<<B,256,0,s>>>(offs, bsum, M);
}
static inline void gemm16(const float* A, const h16* Wp,
                          const float* bias, const float* e1, const float* e2,
                          float* C, int M, int relu, hipStream_t s){
  dim3 grid(CE(EMBD, BCH), CE(M, 64));
  k_gemm16<<<grid,256,0,s>>>(A, LDF, Wp, bias, e1, e2, C, LDF, M, EMBD, relu, 1.0f);
}

extern "C" void kernel_launch(void* const* d_in, const int* in_sizes, int n_in,
                              void* d_out, int out_size, void* d_ws, size_t ws_size,
                              hipStream_t stream) {
  const int*   batch_x   = (const int*)d_in[0];
  const int*   batch_ei  = (const int*)d_in[1];
  const int*   batch_ea  = (const int*)d_in[2];
  const int*   batch_gid = (const int*)d_in[3];
  const int*   frag_x    = (const int*)d_in[4];
  const int*   frag_ei   = (const int*)d_in[5];
  const int*   frag_ea   = (const int*)d_in[6];
  const int*   frag_jid  = (const int*)d_in[7];
  const int*   jct_gid   = (const int*)d_in[8];
  const float* jct_mask  = (const float*)d_in[9];
  const float* ae1       = (const float*)d_in[10];
  const float* ae2       = (const float*)d_in[11];
  const float* gnn_W     = (const float*)d_in[12];
  const float* gnn_b     = (const float*)d_in[13];
  const float* gnn_ee1   = (const float*)d_in[14];
  const float* gnn_ee2   = (const float*)d_in[15];
  const float* bn_gamma  = (const float*)d_in[16];
  const float* bn_beta   = (const float*)d_in[17];
  const float* jct_W     = (const float*)d_in[18];
  const float* jct_b     = (const float*)d_in[19];
  const float* jct_ee1   = (const float*)d_in[20];
  const float* jct_ee2   = (const float*)d_in[21];
  const float* mask_emb  = (const float*)d_in[22];

  const int N = in_sizes[0] / 2;       // 200000
  const int E = in_sizes[1] / 2;       // 400000
  const int NG = 1024, NJ = 8192;
  const int LBLK = CE(N, 64);          // fused-layer grid (3125)

  // workspace carve-up (~258 MB)
  size_t off = 0;
  char* base = (char*)d_ws;
  auto carve = [&](size_t bytes) -> void* {
    void* p = base + off;
    off += (bytes + 255) & ~(size_t)255;
    return p;
  };
  h16*  hA      = (h16*) carve((size_t)(N+1) * HROW * 2);   // +1: zero row N
  h16*  hB      = (h16*) carve((size_t)(N+1) * HROW * 2);
  float* dinv    = (float*)carve((size_t)N * 4);
  int*   degcnt  = (int*)  carve((size_t)N * 4);
  int*   cursor  = degcnt;                       // alias: dead after k_dinv
  int*   counts  = (int*)  carve((size_t)N * 4);
  int*   offs    = (int*)  carve((size_t)(N + 1) * 4);
  int*   entries = (int*)  carve((size_t)(E + N) * 4);
  int*   bsum    = (int*)  carve(1024 * 4);
  float* stats   = (float*)carve(2 * EMBD * 4);
  float* coef    = (float*)carve(2 * HROW * 4);
  h16*  coefh   = (h16*) carve(2 * KEXT * 2);
  h16*  wext    = (h16*) carve((size_t)5 * KEXT * KEXT * 2);
  h16*  wjx     = (h16*) carve((size_t)2 * KEXT * KEXT * 2);
  h16*  htabG   = (h16*) carve((size_t)9 * HROW * 2);
  float* ctab    = (float*)carve((size_t)NTAB * HROW * 4);   // layer-0 tables
  unsigned char* pidx = (unsigned char*)carve((size_t)N);
  float* f0      = (float*)carve((size_t)NG * LDF * 4);
  float* f1      = (float*)carve((size_t)NG * LDF * 4);
  h16*  f1h     = (h16*) carve((size_t)1040 * KEXT * 2);    // logits B (fp16, padded)
  int*   pofs    = (int*)  carve((size_t)(NJ + 1) * 4);      // pool CSR
  int*   pcnt    = (int*)  carve((size_t)NJ * 4);
  int*   perm    = (int*)  carve((size_t)N * 4);
  h16*  spart   = (h16*) carve((size_t)LBLK * SPR * 2);     // 3.8 MB BN partials
  size_t required = off;
  // junction-phase fp32 buffers alias hA (dead when used)
  float* g0      = (float*)hA;
  float* t1      = (float*)((char*)hA + ((size_t)16 << 20));
  float* t2      = (float*)((char*)hA + ((size_t)32 << 20));
  (void)n_in;

  if (ws_size < required || d_ws == nullptr){
    float v = 1.0e6f + (float)(ws_size >> 20) * 1000.0f;   // encode ws MB in absmax
    k_diag<<<CE(out_size,256),256,0,stream>>>((float*)d_out, out_size, v);
    return;
  }

  // one-time prep (ctab depends only on weights -> shared by both branches)
  { dim3 g(KEXT, 5); k_wext<<<g,256,0,stream>>>(gnn_W, gnn_b, gnn_ee1, gnn_ee2, wext); }
  { dim3 g(KEXT, 2); k_wpad<<<g,256,0,stream>>>(jct_W, wjx); }
  k_htab<<<9,256,0,stream>>>(ae1, ae2, htabG);
  k_ctab<<<NTAB,256,0,stream>>>(htabG, wext, ctab);
  hipMemsetAsync(stats, 0, 2*EMBD*4, stream);              // k_bn_coef re-zeros after use
  hipMemsetAsync(hA + (size_t)N*HROW, 0, HROW*2, stream);
  hipMemsetAsync(hB + (size_t)N*HROW, 0, HROW*2, stream);

  for (int br = 0; br < 2; br++){
    const int* x   = br ? frag_x   : batch_x;
    const int* ei  = br ? frag_ei  : batch_ei;
    const int* ea  = br ? frag_ea  : batch_ea;
    const int* gid = br ? frag_jid : batch_gid;
    const int  M   = br ? NJ       : NG;

    // degree (src) + dst-counts in ONE edge pass; then dinv + CSR
    k_init_deg<<<CE(N,256),256,0,stream>>>(degcnt, counts, N);
    k_count_both<<<CE(E,256),256,0,stream>>>(ei, E, degcnt, counts);
    k_dinv<<<CE(N,256),256,0,stream>>>(degcnt, dinv, N);
    scan_excl(counts, N, offs, bsum, stream);
    hipMemsetAsync(cursor, 0, (size_t)N*4, stream);
    k_fill_edges<<<CE(E+N,256),256,0,stream>>>(ei, ea, E, N, offs, cursor, entries);
    k_pidx<<<CE(N,256),256,0,stream>>>(x, pidx, N);

    // pool CSR + permutation (layer 4 writes pool-sorted)
    hipMemsetAsync(pcnt, 0, (size_t)M*4, stream);
    k_count_ids<<<CE(N,256),256,0,stream>>>(gid, N, pcnt);
    scan_excl(pcnt, M, pofs, bsum, stream);
    hipMemsetAsync(cursor, 0, (size_t)M*4, stream);
    k_fill_perm<<<CE(N,256),256,0,stream>>>(gid, N, pofs, cursor, perm);

    // 5 fused layers; layer 0 = 24-table form; layer 4 (PERM=1) writes permuted
    for (int l = 0; l < 5; l++){
      const h16* src = (l & 1) ? hB : hA;
      h16*       dst = (l & 1) ? hA : hB;
      if (l == 0)
        k_layer0<<<LBLK,256,0,stream>>>(pidx, ctab, dinv, offs, counts, entries,
                                        hB, N, spart);
      else if (l == 4)
        k_layer<1,1><<<LBLK,256,0,stream>>>(src, coefh, dinv, offs, counts, entries,
                                            wext + (size_t)l*KEXT*KEXT, dst, N, spart, perm);
      else
        k_layer<1,0><<<LBLK,256,0,stream>>>(src, coefh, dinv, offs, counts, entries,
                                            wext + (size_t)l*KEXT*KEXT, dst, N, spart, nullptr);
      k_red_stats<<<64,256,0,stream>>>(spart, LBLK, stats);
      k_bn_coef<<<CE(KEXT,256),256,0,stream>>>(stats, bn_gamma + l*EMBD, bn_beta + l*EMBD,
                                               coef, coefh, 1.0f/(float)N);
    }
    // hB holds PERMUTED raw layer-4 output; BN affine fused into the pool.

    if (br == 0){
      k_pool_h<<<NG,256,0,stream>>>(hB, pofs, pcnt, g0, coef, nullptr, nullptr);
      gemm16(g0, wjx,
             jct_b, jct_ee1 + 4*EMBD, jct_ee2, t1, NG, 1, stream);
      gemm16(t1, wjx + (size_t)KEXT*KEXT,
             jct_b + EMBD, jct_ee1 + 6*EMBD + 4*EMBD, jct_ee2 + 3*EMBD, f0, NG, 0, stream);
      k_l2norm<<<NG,256,0,stream>>>(f0, NG);
    } else {
      k_pool_h<<<NJ,256,0,stream>>>(hB, pofs, pcnt, t1, coef, jct_mask, mask_emb);
      gemm16(t1, wjx,
             jct_b, jct_ee1 + 4*EMBD, jct_ee2, t2, NJ, 1, stream);
      gemm16(t2, wjx + (size_t)KEXT*KEXT,
             jct_b + EMBD, jct_ee1 + 6*EMBD + 4*EMBD, jct_ee2 + 3*EMBD, t1, NJ, 0, stream);
      // junction -> graph pool (small; entries-based)
      hipMemsetAsync(counts, 0, (size_t)NG*4, stream);
      k_count_ids<<<CE(NJ,256),256,0,stream>>>(jct_gid, NJ, counts);
      scan_excl(counts, NG, offs, bsum, stream);
      hipMemsetAsync(cursor, 0, (size_t)NG*4, stream);
      k_fill_rows<<<CE(NJ,256),256,0,stream>>>(jct_gid, NJ, offs, cursor, entries);
      k_pool_f32<<<NG,256,0,stream>>>(t1, offs, counts, entries, f1, NG);
      k_l2norm<<<NG,256,0,stream>>>(f1, NG);
    }
  }

  // logits = (f0 @ f1^T) / TEMP via MFMA fp16 (f1 -> padded fp16 B-matrix)
  k_f16rows<<<1040,256,0,stream>>>(f1, NG, f1h);
  {
    dim3 grid(CE(NG, BCH), CE(NG, 64));
    k_gemm16<<<grid,256,0,stream>>>(f0, LDF, f1h, nullptr, nullptr, nullptr,
                                    (float*)d_out, 1024, NG, NG, 0, 25.0f);
  }
}

// Round 11
// 3403.016 us; speedup vs baseline: 1.0167x; 1.0163x over previous
//
#include <hip/hip_runtime.h>
#include <math.h>

#define EMBD 300
#define HROW 304     // fp16 h row stride (elements) = 608 B; cols 300-303 = 0
#define LDF  304     // fp32 junction-phase row stride
#define KEXT 320     // extended K: 304 h(+pad) + 1 bias + 6 ee1 + 3 ee2 + 6 pad
#define BCH  80      // B cols per jt chunk (4 chunks of 80 = 320)
#define BSTR 40      // LDS B row stride (halves): 80 B
#define TS2  312     // LDS C-tile row stride (halves): 624 B
#define SPR  608     // spart row stride (halves): [0..299]=sum, [304..603]=sumsq
#define NTAB 24      // layer-0 tables: 9 htab@Wx^T + 15 ext (bt 0..4 x bd 0..2)
#define CE(a,b) (((a)+(b)-1)/(b))

typedef _Float16 h16;
typedef __attribute__((ext_vector_type(8))) _Float16 half8;
typedef __attribute__((ext_vector_type(4))) float f32x4;

// ---------------- utility / CSR kernels ----------------
__global__ void k_diag(float* out, int n, float v){
  int i = blockIdx.x*256 + threadIdx.x;
  if (i < n) out[i] = v;
}
// degcnt = 0, counts = 1 (self-loop) in one pass
__global__ void k_init_deg(int* __restrict__ deg, int* __restrict__ cnts, int N){
  int i = blockIdx.x*256 + threadIdx.x;
  if (i < N){ deg[i] = 0; cnts[i] = 1; }
}
// one pass over edges: src-degree (for dinv) + dst-counts (for CSR)
__global__ void k_count_both(const int* __restrict__ ei, int E,
                             int* __restrict__ deg, int* __restrict__ cnts){
  int e = blockIdx.x*256 + threadIdx.x;
  if (e < E){
    atomicAdd(&deg[ei[e]], 1);
    atomicAdd(&cnts[ei[E + e]], 1);
  }
}
__global__ void k_dinv(const int* __restrict__ deg, float* __restrict__ dinv, int N){
  int i = blockIdx.x*256 + threadIdx.x;
  if (i < N) dinv[i] = 1.0f / sqrtf((float)(deg[i] + 1));   // +1 self-loop
}
__global__ void k_count_ids(const int* __restrict__ ids, int n, int* __restrict__ counts){
  int i = blockIdx.x*256 + threadIdx.x;
  if (i < n) atomicAdd(&counts[ids[i]], 1);
}
__global__ void k_scan_block(const int* __restrict__ in, int M, int* __restrict__ out, int* __restrict__ bsum){
  __shared__ int s[256];
  int t = threadIdx.x, i = blockIdx.x*256 + t;
  int v = (i < M) ? in[i] : 0;
  s[t] = v; __syncthreads();
  for (int off = 1; off < 256; off <<= 1){
    int x = (t >= off) ? s[t-off] : 0;
    __syncthreads();
    s[t] += x;
    __syncthreads();
  }
  if (i < M) out[i] = s[t] - v;
  if (t == 255) bsum[blockIdx.x] = s[255];
}
__global__ void k_scan_sums(int* __restrict__ bsum, int B){   // B <= 1024
  __shared__ int s[1024];
  int t = threadIdx.x;
  int v = (t < B) ? bsum[t] : 0;
  s[t] = v; __syncthreads();
  for (int off = 1; off < 1024; off <<= 1){
    int x = (t >= off) ? s[t-off] : 0;
    __syncthreads();
    s[t] += x;
    __syncthreads();
  }
  if (t < B) bsum[t] = s[t] - v;
}
__global__ void k_scan_add(int* __restrict__ out, const int* __restrict__ bsum, int M){
  int i = blockIdx.x*256 + threadIdx.x;
  if (i < M) out[i] += bsum[blockIdx.x];
}
// entries payload: src | bt<<20 | bd<<23   (src < 2^20)
__global__ void k_fill_edges(const int* __restrict__ ei, const int* __restrict__ ea, int E, int N,
                             const int* __restrict__ offs, int* __restrict__ cur, int* __restrict__ entries){
  int e = blockIdx.x*256 + threadIdx.x;
  if (e < E){
    int s  = ei[e];
    int d  = ei[E + e];
    int bt = ea[2*e], bd = ea[2*e + 1];
    int pos = offs[d] + atomicAdd(&cur[d], 1);
    entries[pos] = s | (bt << 20) | (bd << 23);
  } else if (e < E + N){
    int i = e - E;                          // self-loop: bond type 4, dir 0
    int pos = offs[i] + atomicAdd(&cur[i], 1);
    entries[pos] = i | (4 << 20);
  }
}
__global__ void k_fill_rows(const int* __restrict__ ids, int n, const int* __restrict__ offs,
                            int* __restrict__ cur, int* __restrict__ entries){
  int i = blockIdx.x*256 + threadIdx.x;
  if (i < n){
    int g = ids[i];
    int pos = offs[g] + atomicAdd(&cur[g], 1);
    entries[pos] = i;
  }
}

// ---------------- model kernels ----------------
// h0 has only 9 distinct rows (x entries are in [0,3)): htab[p] = ae1[p/3]+ae2[p%3]
__global__ void k_htab(const float* __restrict__ ae1, const float* __restrict__ ae2,
                       h16* __restrict__ htab){
  int p = blockIdx.x;                 // 0..8
  int a = p / 3, b = p % 3;
  int t = threadIdx.x;
  h16* d = htab + (size_t)p*HROW;
  for (int c = t; c < HROW; c += 256)
    d[c] = (c < EMBD) ? (h16)(ae1[(size_t)a*EMBD + c] + ae2[(size_t)b*EMBD + c]) : (h16)0.f;
}
__global__ void k_pidx(const int* __restrict__ x, unsigned char* __restrict__ pidx, int N){
  int i = blockIdx.x*256 + threadIdx.x;
  if (i < N) pidx[i] = (unsigned char)(x[2*i]*3 + x[2*i+1]);
}
// layer-0 tables: ctab[q][o].  q<9: htab[q] @ Wx[o]^T (fp16 ops, f32 accum).
// q>=9: Wx[o][304] + Wx[o][305+bt] + Wx[o][311+bd].
__global__ void k_ctab(const h16* __restrict__ htabG, const h16* __restrict__ Wx,
                       float* __restrict__ ctab){
  int q = blockIdx.x, t = threadIdx.x;
  float* d = ctab + (size_t)q*HROW;
  if (q < 9){
    const h16* hr = htabG + (size_t)q*HROW;
    for (int o = t; o < HROW; o += 256){
      float s = 0.f;
      if (o < EMBD){
        const h16* wr = Wx + (size_t)o*KEXT;
        for (int k = 0; k < EMBD; k++)
          s += (float)hr[k] * (float)wr[k];
      }
      d[o] = s;
    }
  } else {
    int bt = (q - 9) / 3, bd = (q - 9) % 3;
    for (int o = t; o < HROW; o += 256){
      float s = 0.f;
      if (o < EMBD){
        const h16* wr = Wx + (size_t)o*KEXT;
        s = (float)wr[304] + (float)wr[305 + bt] + (float)wr[311 + bd];
      }
      d[o] = s;
    }
  }
}

// extended weights (fp16): Wx[l][o][k], o,k in [0,KEXT)
// k<300: W[o][k]; k==304: b[o]; 305..310: ee1; 311..313: ee2; else 0
__global__ void k_wext(const float* __restrict__ W, const float* __restrict__ b,
                       const float* __restrict__ ee1, const float* __restrict__ ee2,
                       h16* __restrict__ out){
  int l = blockIdx.y, o = blockIdx.x, t = threadIdx.x;
  h16* d = out + ((size_t)l*KEXT + o)*KEXT;
  for (int k = t; k < KEXT; k += 256){
    float v = 0.f;
    if (o < EMBD){
      if      (k < EMBD)            v = W[(size_t)l*EMBD*EMBD + (size_t)o*EMBD + k];
      else if (k == 304)            v = b[l*EMBD + o];
      else if (k >= 305 && k < 311) v = ee1[((size_t)l*6 + (k-305))*EMBD + o];
      else if (k >= 311 && k < 314) v = ee2[((size_t)l*3 + (k-311))*EMBD + o];
    }
    d[k] = (h16)v;
  }
}
// plain fp16 zero-pad of jct_W: wjx[l][o][k], 320x320, grid (KEXT, 2)
__global__ void k_wpad(const float* __restrict__ W, h16* __restrict__ out){
  int l = blockIdx.y, o = blockIdx.x, t = threadIdx.x;
  h16* d = out + ((size_t)l*KEXT + o)*KEXT;
  for (int k = t; k < KEXT; k += 256)
    d[k] = (h16)((o < EMBD && k < EMBD) ? W[(size_t)l*EMBD*EMBD + (size_t)o*EMBD + k] : 0.f);
}
// f32 rows [M][LDF] -> fp16 rows [Mpad][KEXT] (zero-padded), for MFMA B operand
__global__ void k_f16rows(const float* __restrict__ src, int M, h16* __restrict__ dst){
  int r = blockIdx.x, t = threadIdx.x;
  h16* d = dst + (size_t)r*KEXT;
  for (int k = t; k < KEXT; k += 256)
    d[k] = (h16)((r < M && k < EMBD) ? src[(size_t)r*LDF + k] : 0.f);
}

// BN affine from stats: fp32 (for pooled rows) + fp16 (for gather).
// Also RE-ZEROS stats for the next layer (drops the per-layer memset).
__global__ void k_bn_coef(float* __restrict__ stats, const float* __restrict__ gamma,
                          const float* __restrict__ beta, float* __restrict__ coef,
                          h16* __restrict__ coefh, float invN){
  int c = blockIdx.x*256 + threadIdx.x;
  if (c >= KEXT) return;
  float sc = 0.f, sh = 0.f;
  if (c < EMBD){
    float mu  = stats[c]*invN;
    float var = stats[EMBD + c]*invN - mu*mu;
    sc = gamma[c]*rsqrtf(var + 1e-5f);
    sh = beta[c] - mu*sc;
    stats[c] = 0.f; stats[EMBD + c] = 0.f;
  }
  if (c < HROW){ coef[c] = sc; coef[HROW + c] = sh; }
  coefh[c] = (h16)sc; coefh[KEXT + c] = (h16)sh;
}

// reduce per-block fp16 stat partials -> stats[600] (f32)
__global__ void k_red_stats(const h16* __restrict__ spart, int nb, float* __restrict__ stats){
  int t = threadIdx.x;
  int c1 = t + 256;                      // valid only for t < 44
  float a0 = 0.f, q0 = 0.f, a1 = 0.f, q1 = 0.f;
  for (int b = blockIdx.x; b < nb; b += gridDim.x){
    const h16* sp = spart + (size_t)b*SPR;
    a0 += (float)sp[t];
    q0 += (float)sp[304 + t];
    if (c1 < EMBD){ a1 += (float)sp[c1]; q1 += (float)sp[304 + c1]; }
  }
  if (t < EMBD){ atomicAdd(&stats[t], a0); atomicAdd(&stats[EMBD + t], q0); }
  if (c1 < EMBD){ atomicAdd(&stats[c1], a1); atomicAdd(&stats[EMBD + c1], q1); }
}

// ---- fused layer (layers 1-4): fixed-8 fan-out gather -> MFMA -> BN stats ----
// UNCHANGED from round 7 (best measured config, 3428 us total): bytes at floor,
// BW pinned ~2.3 TB/s across 21-41% occupancy -> L2-miss random-line roofline.
template<int RELU>
__global__ void __launch_bounds__(256)
k_layer(const h16* __restrict__ hRaw, const h16* __restrict__ coefh,
        const float* __restrict__ dinv,
        const int* __restrict__ offs, const int* __restrict__ counts,
        const int* __restrict__ entries, const h16* __restrict__ Wx,
        h16* __restrict__ hOut, int N, h16* __restrict__ spart)
{
  __shared__ h16  tile[64][TS2];       // 39.9 KB persistent C tile
  __shared__ h16  Bs[BCH][BSTR];       //  6.4 KB B chunk (80 cols x 32 k)
  __shared__ float sred[2*HROW];       //  2.4 KB BN partials
  __shared__ int   rstart[64];
  __shared__ int   rcnt[64];
  __shared__ float dvv[64];

  int tid = threadIdx.x;
  int wid = tid >> 6, lane = tid & 63;
  int m16 = lane & 15, ko = lane >> 4;
  long row0 = (long)blockIdx.x * 64;

  if (tid < 64){
    long g = row0 + tid;
    int o = 0, c = 0; float d = 0.f;
    if (g < N){ o = offs[g]; c = counts[g]; d = dinv[g]; }
    rstart[tid] = o; rcnt[tid] = c; dvv[tid] = d;
  }
  for (int i = tid; i < 2*HROW; i += 256) sred[i] = 0.f;
  __syncthreads();

  int lr = wid*16 + m16;
  int myStart = rstart[lr], myCnt = rcnt[lr];
  float di = dvv[lr];

  // ---- prefetch up to 8 edge descriptors + weights ----
  int srcA[8]; float wvA[8]; int eA[8];
  #pragma unroll
  for (int j = 0; j < 8; j++){
    int e = entries[myStart + j];               // bounded over-read ok (within ws)
    bool act = j < myCnt;
    int s = act ? (e & 0xFFFFF) : N;            // row N is all-zero
    float wv = dinv[act ? s : 0];
    wvA[j] = act ? wv : 0.f;
    srcA[j] = s; eA[j] = e;
  }
  float ext[8] = {0,0,0,0,0,0,0,0};
  if (ko >= 2){
    int extbase = (ko - 2)*8;
    #pragma unroll
    for (int j = 0; j < 8; j++){
      unsigned msk = 1u | (1u << (1 + ((eA[j] >> 20) & 7))) | (1u << (7 + ((eA[j] >> 23) & 3)));
      #pragma unroll
      for (int c = 0; c < 8; c++)
        ext[c] += ((msk >> (extbase + c)) & 1u) ? wvA[j] : 0.f;
    }
  }
  half8 wvh[8];
  #pragma unroll
  for (int j = 0; j < 8; j++){
    _Float16 w = (_Float16)wvA[j];
    #pragma unroll
    for (int c = 0; c < 8; c++) wvh[j][c] = w;
  }

  half8 acc[10];
  #pragma unroll
  for (int k = 0; k < 10; k++) acc[k] = (half8)(_Float16)0;

  // ---- rare overflow: rows with cnt > 8 (per-lane divergent) ----
  if (__any(myCnt > 8)){
    for (int j = 8; j < myCnt; j++){
      int e = entries[myStart + j];
      int s = e & 0xFFFFF;
      float wv = dinv[s];
      if (ko >= 2){
        int extbase = (ko - 2)*8;
        unsigned msk = 1u | (1u << (1 + ((e >> 20) & 7))) | (1u << (7 + ((e >> 23) & 3)));
        #pragma unroll
        for (int c = 0; c < 8; c++)
          ext[c] += ((msk >> (extbase + c)) & 1u) ? wv : 0.f;
      }
      _Float16 wh = (_Float16)wv;
      half8 w8;
      #pragma unroll
      for (int c = 0; c < 8; c++) w8[c] = wh;
      #pragma unroll
      for (int k = 0; k < 10; k++){
        if (k == 9 && ko >= 2) break;
        half8 sck = *(const half8*)&coefh[k*32 + ko*8];
        half8 shk = *(const half8*)&coefh[KEXT + k*32 + ko*8];
        half8 x = *(const half8*)(hRaw + (size_t)s*HROW + k*32 + ko*8);
        half8 y = sck*x + shk;
        if (RELU){
          #pragma unroll
          for (int c = 0; c < 8; c++) y[c] = y[c] > (_Float16)0 ? y[c] : (_Float16)0;
        }
        acc[k] += w8*y;
      }
    }
  }

  // ---- main gather: chunk-outer, fixed 8 edges inner (8 loads in flight) ----
  #pragma unroll
  for (int k = 0; k < 9; k++){
    half8 sck = *(const half8*)&coefh[k*32 + ko*8];
    half8 shk = *(const half8*)&coefh[KEXT + k*32 + ko*8];
    half8 a = acc[k];
    #pragma unroll
    for (int j = 0; j < 8; j++){
      half8 x = *(const half8*)(hRaw + (size_t)srcA[j]*HROW + k*32 + ko*8);
      half8 y = sck*x + shk;
      if (RELU){
        #pragma unroll
        for (int c = 0; c < 8; c++) y[c] = y[c] > (_Float16)0 ? y[c] : (_Float16)0;
      }
      a += wvh[j]*y;
    }
    acc[k] = a;
  }
  { // k = 9: ko<2 covers cols 288-303 (coef 300-303 = 0); ko>=2 = ext scalars
    half8 a = acc[9];
    if (ko < 2){
      half8 sck = *(const half8*)&coefh[288 + ko*8];
      half8 shk = *(const half8*)&coefh[KEXT + 288 + ko*8];
      #pragma unroll
      for (int j = 0; j < 8; j++){
        half8 x = *(const half8*)(hRaw + (size_t)srcA[j]*HROW + 288 + ko*8);
        half8 y = sck*x + shk;
        if (RELU){
          #pragma unroll
          for (int c = 0; c < 8; c++) y[c] = y[c] > (_Float16)0 ? y[c] : (_Float16)0;
        }
        a += wvh[j]*y;
      }
    } else {
      #pragma unroll
      for (int c = 0; c < 8; c++) a[c] += (_Float16)ext[c];
    }
    acc[9] = a;
  }

  // scale by dinv[dst]
  half8 afr[10];
  {
    _Float16 dh = (_Float16)di;
    half8 d8;
    #pragma unroll
    for (int c = 0; c < 8; c++) d8[c] = dh;
    #pragma unroll
    for (int k = 0; k < 10; k++) afr[k] = acc[k] * d8;
  }

  // ---- GEMM over 4 col-chunks of 80; C staged to persistent LDS tile ----
  int cr = ko * 4;
  #pragma unroll
  for (int jt = 0; jt < 4; jt++){
    f32x4 a2[5];
    #pragma unroll
    for (int j = 0; j < 5; j++) a2[j] = (f32x4){0.f,0.f,0.f,0.f};
    for (int k0 = 0; k0 < 10; k0++){
      __syncthreads();
      for (int idx = tid; idx < 320; idx += 256){
        int o = idx >> 2, qd = (idx & 3) * 8;
        *(half8*)&Bs[o][qd] = *(const half8*)(Wx + (size_t)(jt*BCH + o)*KEXT + k0*32 + qd);
      }
      __syncthreads();
      #pragma unroll
      for (int j = 0; j < 5; j++){
        half8 bfr = *(const half8*)&Bs[j*16 + m16][ko*8];
        a2[j] = __builtin_amdgcn_mfma_f32_16x16x32_f16(afr[k0], bfr, a2[j], 0, 0, 0);
      }
    }
    // BN partials from registers (LDS atomics only)
    #pragma unroll
    for (int j = 0; j < 5; j++){
      int col = jt*BCH + j*16 + m16;
      float s = 0.f, q = 0.f;
      #pragma unroll
      for (int r = 0; r < 4; r++){
        float v = a2[j][r];
        s += v; q += v*v;
      }
      s += __shfl_xor(s, 16, 64); s += __shfl_xor(s, 32, 64);
      q += __shfl_xor(q, 16, 64); q += __shfl_xor(q, 32, 64);
      if (ko == 0 && col < EMBD){
        atomicAdd(&sred[col], s);
        atomicAdd(&sred[HROW + col], q);
      }
    }
    // stage to tile (wave-private rows: no barrier needed)
    #pragma unroll
    for (int j = 0; j < 5; j++){
      int col = jt*BCH + j*16 + m16;
      if (col < HROW){
        #pragma unroll
        for (int r = 0; r < 4; r++)
          tile[wid*16 + cr + r][col] = (h16)a2[j][r];
      }
    }
  }
  __syncthreads();
  // ---- single coalesced writeout: full 608 B rows, each line written once ----
  for (int idx = tid; idx < 64*38; idx += 256){
    int row = idx / 38, c = idx - row*38;
    long grow = row0 + row;
    if (grow < N)
      *(uint4*)(hOut + grow*HROW + c*8) = *(const uint4*)&tile[row][c*8];
  }
  // ---- BN partials -> per-block fp16 slab (no global atomics) ----
  h16* sp = spart + (size_t)blockIdx.x*SPR;
  for (int c = tid; c < EMBD; c += 256){
    sp[c]       = (h16)sred[c];
    sp[304 + c] = (h16)sred[HROW + c];
  }
}

// ---- layer 0, table form: out[d] = dinv[d] * sum_q coef_q(d) * ctab[q] ----
__global__ void __launch_bounds__(256)
k_layer0(const unsigned char* __restrict__ pidx, const float* __restrict__ ctab,
         const float* __restrict__ dinv,
         const int* __restrict__ offs, const int* __restrict__ counts,
         const int* __restrict__ entries,
         h16* __restrict__ hOut, int N, h16* __restrict__ spart)
{
  __shared__ float tabs[NTAB][HROW];   // 29.2 KB
  __shared__ float cf[64][NTAB];       //  6.0 KB
  __shared__ float sred[2*HROW];       //  2.4 KB
  int tid = threadIdx.x;
  long row0 = (long)blockIdx.x * 64;

  for (int i = tid; i < NTAB*HROW; i += 256) ((float*)tabs)[i] = ctab[i];
  for (int i = tid; i < 64*NTAB; i += 256) ((float*)cf)[i] = 0.f;
  for (int i = tid; i < 2*HROW; i += 256) sred[i] = 0.f;
  __syncthreads();

  if (tid < 64){
    long g = row0 + tid;
    if (g < N){
      int o = offs[g], c = counts[g];
      float dv = dinv[g];
      float* cr = cf[tid];
      for (int j = 0; j < c; j++){
        int e = entries[o + j];
        int s = e & 0xFFFFF;
        int bt = (e >> 20) & 7, bd = (e >> 23) & 3;
        float wv = dinv[s];
        cr[pidx[s]] += wv;
        cr[9 + bt*3 + bd] += wv;
      }
      #pragma unroll
      for (int q = 0; q < NTAB; q++) cr[q] *= dv;   // fold dinv[dst]
    }
  }
  __syncthreads();

  // output: work item w = (row-group rg of 8 rows) x (16B col-chunk c of 38)
  for (int w = tid; w < 8*38; w += 256){
    int c = w % 38, rg = w / 38;
    float v[8][8];
    #pragma unroll
    for (int r = 0; r < 8; r++)
      #pragma unroll
      for (int cc = 0; cc < 8; cc++) v[r][cc] = 0.f;
    for (int q = 0; q < NTAB; q++){
      float tr[8];
      #pragma unroll
      for (int cc = 0; cc < 8; cc++) tr[cc] = tabs[q][c*8 + cc];
      #pragma unroll
      for (int r = 0; r < 8; r++){
        float co = cf[rg*8 + r][q];
        #pragma unroll
        for (int cc = 0; cc < 8; cc++) v[r][cc] += co * tr[cc];
      }
    }
    float s[8], qq[8];
    #pragma unroll
    for (int cc = 0; cc < 8; cc++){ s[cc] = 0.f; qq[cc] = 0.f; }
    #pragma unroll
    for (int r = 0; r < 8; r++){
      long grow = row0 + rg*8 + r;
      if (grow < N){
        half8 hv;
        #pragma unroll
        for (int cc = 0; cc < 8; cc++){
          float x = v[r][cc];
          hv[cc] = (h16)x;
          s[cc] += x; qq[cc] += x*x;
        }
        *(half8*)(hOut + grow*HROW + c*8) = hv;
      }
    }
    #pragma unroll
    for (int cc = 0; cc < 8; cc++){
      atomicAdd(&sred[c*8 + cc], s[cc]);
      atomicAdd(&sred[HROW + c*8 + cc], qq[cc]);
    }
  }
  __syncthreads();
  h16* sp = spart + (size_t)blockIdx.x*SPR;
  for (int c = tid; c < EMBD; c += 256){
    sp[c]       = (h16)sred[c];
    sp[304 + c] = (h16)sred[HROW + c];
  }
}

// mean-pool of fp16 rows + fused BN affine (+ optional mask overwrite)
__global__ void k_pool_h(const h16* __restrict__ h, const int* __restrict__ offs,
                         const int* __restrict__ counts, const int* __restrict__ entries,
                         float* __restrict__ out, const float* __restrict__ coef,
                         const float* __restrict__ mask, const float* __restrict__ memb){
  int g = blockIdx.x, t = threadIdx.x, c1 = t + 256;
  int off = offs[g], cnt = counts[g];
  float a0 = 0.f, a1 = 0.f;
  int j = 0;
  for (; j + 4 <= cnt; j += 4){          // 4 rows in flight
    int r0 = entries[off+j],   r1 = entries[off+j+1];
    int r2 = entries[off+j+2], r3 = entries[off+j+3];
    const h16* p0 = h + (size_t)r0*HROW;
    const h16* p1 = h + (size_t)r1*HROW;
    const h16* p2 = h + (size_t)r2*HROW;
    const h16* p3 = h + (size_t)r3*HROW;
    float x0 = (float)p0[t], x1 = (float)p1[t];
    float x2 = (float)p2[t], x3 = (float)p3[t];
    a0 += (x0 + x1) + (x2 + x3);
    if (c1 < EMBD){
      float y0 = (float)p0[c1], y1 = (float)p1[c1];
      float y2 = (float)p2[c1], y3 = (float)p3[c1];
      a1 += (y0 + y1) + (y2 + y3);
    }
  }
  for (; j < cnt; j++){
    int r = entries[off + j];
    const h16* hr = h + (size_t)r*HROW;
    a0 += (float)hr[t];
    if (c1 < EMBD) a1 += (float)hr[c1];
  }
  float inv = 1.0f / fmaxf((float)cnt, 1.0f);
  float v0 = coef[t]*(a0*inv) + coef[HROW + t];
  float v1 = (c1 < EMBD) ? coef[c1]*(a1*inv) + coef[HROW + c1] : 0.f;
  if (mask && mask[g] > 0.5f){
    v0 = memb[t];
    if (c1 < EMBD) v1 = memb[c1];
  }
  float* o = out + (size_t)g*LDF;
  o[t] = v0;
  if (c1 < EMBD) o[c1] = v1;
}
__global__ void k_pool_f32(const float* __restrict__ h, const int* __restrict__ offs,
                           const int* __restrict__ counts, const int* __restrict__ entries,
                           float* __restrict__ out, int M){
  int g = blockIdx.x, t = threadIdx.x, c1 = t + 256;
  int off = offs[g], cnt = counts[g];
  float a0 = 0.f, a1 = 0.f;
  for (int j = 0; j < cnt; j++){
    int r = entries[off + j];
    const float* hr = h + (size_t)r*LDF;
    a0 += hr[t];
    if (c1 < EMBD) a1 += hr[c1];
  }
  float inv = 1.0f / fmaxf((float)cnt, 1.0f);
  float* o = out + (size_t)g*LDF;
  o[t] = a0*inv;
  if (c1 < EMBD) o[c1] = a1*inv;
}

__global__ void k_l2norm(float* __restrict__ f, int M){
  int g = blockIdx.x, t = threadIdx.x, c1 = t + 256;
  float* fr = f + (size_t)g*LDF;
  float v0 = fr[t];
  float v1 = (c1 < EMBD) ? fr[c1] : 0.f;
  float ss = v0*v0 + v1*v1;
  #pragma unroll
  for (int o = 32; o > 0; o >>= 1) ss += __shfl_down(ss, o, 64);
  __shared__ float red[4];
  int wid = t >> 6, lane = t & 63;
  if (lane == 0) red[wid] = ss;
  __syncthreads();
  if (t == 0) red[0] = 1.0f / fmaxf(sqrtf(red[0]+red[1]+red[2]+red[3]), 1e-12f);
  __syncthreads();
  float inv = red[0];
  fr[t] = v0*inv;
  if (c1 < EMBD) fr[c1] = v1*inv;
}

// ---- MFMA fp16 GEMM: C = (A(f32) @ Wp(fp16)^T + adds) * scale ----
// Wp rows are KEXT-stride fp16 with cols >=300 zero.
__global__ void __launch_bounds__(256)
k_gemm16(const float* __restrict__ A, int lda, const h16* __restrict__ Wp,
         const float* __restrict__ bias, const float* __restrict__ e1, const float* __restrict__ e2,
         float* __restrict__ C, int ldc, int M, int Ncols, int relu, float scale)
{
  __shared__ h16 Bs[BCH][BSTR];        // 6.4 KB
  int tid = threadIdx.x;
  int wid = tid >> 6, lane = tid & 63;
  int m16 = lane & 15, ko = lane >> 4;
  int row0 = blockIdx.y * 64;
  int col0 = blockIdx.x * BCH;
  int arow = row0 + wid*16 + m16;
  bool rok = arow < M;
  const float* Ar = A + (size_t)(rok ? arow : 0) * lda;

  half8 afr[10];
  #pragma unroll
  for (int k0 = 0; k0 < 9; k0++){
    const float* p = Ar + k0*32 + ko*8;
    float4 fa = rok ? *(const float4*)p       : (float4){0.f,0.f,0.f,0.f};
    float4 fb = rok ? *(const float4*)(p + 4) : (float4){0.f,0.f,0.f,0.f};
    half8 v;
    v[0]=(h16)fa.x; v[1]=(h16)fa.y; v[2]=(h16)fa.z; v[3]=(h16)fa.w;
    v[4]=(h16)fb.x; v[5]=(h16)fb.y; v[6]=(h16)fb.z; v[7]=(h16)fb.w;
    afr[k0] = v;
  }
  {
    half8 v;
    #pragma unroll
    for (int c = 0; c < 8; c++){
      int ch = 288 + ko*8 + c;
      v[c] = (h16)((rok && ch < EMBD) ? Ar[ch] : 0.f);
    }
    afr[9] = v;
  }

  f32x4 a2[5];
  #pragma unroll
  for (int j = 0; j < 5; j++) a2[j] = (f32x4){0.f,0.f,0.f,0.f};
  for (int k0 = 0; k0 < 10; k0++){
    __syncthreads();
    for (int idx = tid; idx < 320; idx += 256){
      int o = idx >> 2, qd = (idx & 3) * 8;
      *(half8*)&Bs[o][qd] = *(const half8*)(Wp + (size_t)(col0 + o)*KEXT + k0*32 + qd);
    }
    __syncthreads();
    #pragma unroll
    for (int j = 0; j < 5; j++){
      half8 bfr = *(const half8*)&Bs[j*16 + m16][ko*8];
      a2[j] = __builtin_amdgcn_mfma_f32_16x16x32_f16(afr[k0], bfr, a2[j], 0, 0, 0);
    }
  }
  #pragma unroll
  for (int j = 0; j < 5; j++){
    int cc = col0 + j*16 + m16;
    if (cc >= Ncols) continue;
    float add = bias ? (bias[cc] + e1[cc] + e2[cc]) : 0.f;
    #pragma unroll
    for (int r = 0; r < 4; r++){
      int rr = row0 + wid*16 + ko*4 + r;
      if (rr >= M) continue;
      float v = (a2[j][r] + add) * scale;
      if (relu) v = fmaxf(v, 0.f);
      C[(size_t)rr*ldc + cc] = v;
    }
  }
}

// ---------------- host side ----------------
static inline void scan_excl(const int* counts, int M, int* offs, int* bsum, hipStream_t s){
  int B = CE(M, 256);
  k_scan_block<<<B,256,0,s>>>(counts, M, offs, bsum);
  k_scan_sums<<<1,1024,0,s>>>(bsum, B);
  k_scan_add<<<B,256,0,s>>>(offs, bsum, M);
}
static inline void gemm16(const float* A, const h16* Wp,
                          const float* bias, const float* e1, const float* e2,
                          float* C, int M, int relu, hipStream_t s){
  dim3 grid(CE(EMBD, BCH), CE(M, 64));
  k_gemm16<<<grid,256,0,s>>>(A, LDF, Wp, bias, e1, e2, C, LDF, M, EMBD, relu, 1.0f);
}

extern "C" void kernel_launch(void* const* d_in, const int* in_sizes, int n_in,
                              void* d_out, int out_size, void* d_ws, size_t ws_size,
                              hipStream_t stream) {
  const int*   batch_x   = (const int*)d_in[0];
  const int*   batch_ei  = (const int*)d_in[1];
  const int*   batch_ea  = (const int*)d_in[2];
  const int*   batch_gid = (const int*)d_in[3];
  const int*   frag_x    = (const int*)d_in[4];
  const int*   frag_ei   = (const int*)d_in[5];
  const int*   frag_ea   = (const int*)d_in[6];
  const int*   frag_jid  = (const int*)d_in[7];
  const int*   jct_gid   = (const int*)d_in[8];
  const float* jct_mask  = (const float*)d_in[9];
  const float* ae1       = (const float*)d_in[10];
  const float* ae2       = (const float*)d_in[11];
  const float* gnn_W     = (const float*)d_in[12];
  const float* gnn_b     = (const float*)d_in[13];
  const float* gnn_ee1   = (const float*)d_in[14];
  const float* gnn_ee2   = (const float*)d_in[15];
  const float* bn_gamma  = (const float*)d_in[16];
  const float* bn_beta   = (const float*)d_in[17];
  const float* jct_W     = (const float*)d_in[18];
  const float* jct_b     = (const float*)d_in[19];
  const float* jct_ee1   = (const float*)d_in[20];
  const float* jct_ee2   = (const float*)d_in[21];
  const float* mask_emb  = (const float*)d_in[22];

  const int N = in_sizes[0] / 2;       // 200000
  const int E = in_sizes[1] / 2;       // 400000
  const int NG = 1024, NJ = 8192;
  const int LBLK = CE(N, 64);          // fused-layer grid (3125)

  // workspace carve-up (~257 MB)
  size_t off = 0;
  char* base = (char*)d_ws;
  auto carve = [&](size_t bytes) -> void* {
    void* p = base + off;
    off += (bytes + 255) & ~(size_t)255;
    return p;
  };
  h16*  hA      = (h16*) carve((size_t)(N+1) * HROW * 2);   // +1: zero row N
  h16*  hB      = (h16*) carve((size_t)(N+1) * HROW * 2);
  float* dinv    = (float*)carve((size_t)N * 4);
  int*   degcnt  = (int*)  carve((size_t)N * 4);
  int*   cursor  = degcnt;                       // alias: dead after k_dinv
  int*   counts  = (int*)  carve((size_t)N * 4);
  int*   offs    = (int*)  carve((size_t)(N + 1) * 4);
  int*   entries = (int*)  carve((size_t)(E + N) * 4);
  int*   bsum    = (int*)  carve(1024 * 4);
  float* stats   = (float*)carve(2 * EMBD * 4);
  float* coef    = (float*)carve(2 * HROW * 4);
  h16*  coefh   = (h16*) carve(2 * KEXT * 2);
  h16*  wext    = (h16*) carve((size_t)5 * KEXT * KEXT * 2);
  h16*  wjx     = (h16*) carve((size_t)2 * KEXT * KEXT * 2);
  h16*  htabG   = (h16*) carve((size_t)9 * HROW * 2);
  float* ctab    = (float*)carve((size_t)NTAB * HROW * 4);   // layer-0 tables
  unsigned char* pidx = (unsigned char*)carve((size_t)N);
  float* f0      = (float*)carve((size_t)NG * LDF * 4);
  float* f1      = (float*)carve((size_t)NG * LDF * 4);
  h16*  f1h     = (h16*) carve((size_t)1040 * KEXT * 2);    // logits B (fp16, padded)
  h16*  spart   = (h16*) carve((size_t)LBLK * SPR * 2);     // 3.8 MB BN partials
  size_t required = off;
  // junction-phase fp32 buffers alias hA (dead when used)
  float* g0      = (float*)hA;
  float* t1      = (float*)((char*)hA + ((size_t)16 << 20));
  float* t2      = (float*)((char*)hA + ((size_t)32 << 20));
  (void)n_in;

  if (ws_size < required || d_ws == nullptr){
    float v = 1.0e6f + (float)(ws_size >> 20) * 1000.0f;   // encode ws MB in absmax
    k_diag<<<CE(out_size,256),256,0,stream>>>((float*)d_out, out_size, v);
    return;
  }

  // one-time prep (ctab depends only on weights -> shared by both branches)
  { dim3 g(KEXT, 5); k_wext<<<g,256,0,stream>>>(gnn_W, gnn_b, gnn_ee1, gnn_ee2, wext); }
  { dim3 g(KEXT, 2); k_wpad<<<g,256,0,stream>>>(jct_W, wjx); }
  k_htab<<<9,256,0,stream>>>(ae1, ae2, htabG);
  k_ctab<<<NTAB,256,0,stream>>>(htabG, wext, ctab);
  hipMemsetAsync(stats, 0, 2*EMBD*4, stream);              // k_bn_coef re-zeros after use
  hipMemsetAsync(hA + (size_t)N*HROW, 0, HROW*2, stream);
  hipMemsetAsync(hB + (size_t)N*HROW, 0, HROW*2, stream);

  for (int br = 0; br < 2; br++){
    const int* x  = br ? frag_x  : batch_x;
    const int* ei = br ? frag_ei : batch_ei;
    const int* ea = br ? frag_ea : batch_ea;

    // degree (src) + dst-counts in ONE edge pass; then dinv + CSR
    k_init_deg<<<CE(N,256),256,0,stream>>>(degcnt, counts, N);
    k_count_both<<<CE(E,256),256,0,stream>>>(ei, E, degcnt, counts);
    k_dinv<<<CE(N,256),256,0,stream>>>(degcnt, dinv, N);
    scan_excl(counts, N, offs, bsum, stream);
    hipMemsetAsync(cursor, 0, (size_t)N*4, stream);
    k_fill_edges<<<CE(E+N,256),256,0,stream>>>(ei, ea, E, N, offs, cursor, entries);
    k_pidx<<<CE(N,256),256,0,stream>>>(x, pidx, N);

    // 5 fused layers; layer 0 is the 24-table form (no MFMA, no h0 gather)
    for (int l = 0; l < 5; l++){
      const h16* src = (l & 1) ? hB : hA;
      h16*       dst = (l & 1) ? hA : hB;
      if (l == 0)
        k_layer0<<<LBLK,256,0,stream>>>(pidx, ctab, dinv, offs, counts, entries,
                                        hB, N, spart);
      else
        k_layer<1><<<LBLK,256,0,stream>>>(src, coefh, dinv, offs, counts, entries,
                                          wext + (size_t)l*KEXT*KEXT, dst, N, spart);
      k_red_stats<<<64,256,0,stream>>>(spart, LBLK, stats);
      k_bn_coef<<<CE(KEXT,256),256,0,stream>>>(stats, bn_gamma + l*EMBD, bn_beta + l*EMBD,
                                               coef, coefh, 1.0f/(float)N);
    }
    // hB holds raw layer-4 lin output; coef holds its BN affine (no relu on last layer):
    // BN commutes with mean-pool -> affine fused into the pool epilogue.

    if (br == 0){
      hipMemsetAsync(counts, 0, (size_t)NG*4, stream);
      k_count_ids<<<CE(N,256),256,0,stream>>>(batch_gid, N, counts);
      scan_excl(counts, NG, offs, bsum, stream);
      hipMemsetAsync(cursor, 0, (size_t)NG*4, stream);
      k_fill_rows<<<CE(N,256),256,0,stream>>>(batch_gid, N, offs, cursor, entries);
      k_pool_h<<<NG,256,0,stream>>>(hB, offs, counts, entries, g0, coef, nullptr, nullptr);
      gemm16(g0, wjx,
             jct_b, jct_ee1 + 4*EMBD, jct_ee2, t1, NG, 1, stream);
      gemm16(t1, wjx + (size_t)KEXT*KEXT,
             jct_b + EMBD, jct_ee1 + 6*EMBD + 4*EMBD, jct_ee2 + 3*EMBD, f0, NG, 0, stream);
      k_l2norm<<<NG,256,0,stream>>>(f0, NG);
    } else {
      hipMemsetAsync(counts, 0, (size_t)NJ*4, stream);
      k_count_ids<<<CE(N,256),256,0,stream>>>(frag_jid, N, counts);
      scan_excl(counts, NJ, offs, bsum, stream);
      hipMemsetAsync(cursor, 0, (size_t)NJ*4, stream);
      k_fill_rows<<<CE(N,256),256,0,stream>>>(frag_jid, N, offs, cursor, entries);
      k_pool_h<<<NJ,256,0,stream>>>(hB, offs, counts, entries, t1, coef, jct_mask, mask_emb);
      gemm16(t1, wjx,
             jct_b, jct_ee1 + 4*EMBD, jct_ee2, t2, NJ, 1, stream);
      gemm16(t2, wjx + (size_t)KEXT*KEXT,
             jct_b + EMBD, jct_ee1 + 6*EMBD + 4*EMBD, jct_ee2 + 3*EMBD, t1, NJ, 0, stream);
      hipMemsetAsync(counts, 0, (size_t)NG*4, stream);
      k_count_ids<<<CE(NJ,256),256,0,stream>>>(jct_gid, NJ, counts);
      scan_excl(counts, NG, offs, bsum, stream);
      hipMemsetAsync(cursor, 0, (size_t)NG*4, stream);
      k_fill_rows<<<CE(NJ,256),256,0,stream>>>(jct_gid, NJ, offs, cursor, entries);
      k_pool_f32<<<NG,256,0,stream>>>(t1, offs, counts, entries, f1, NG);
      k_l2norm<<<NG,256,0,stream>>>(f1, NG);
    }
  }

  // logits = (f0 @ f1^T) / TEMP via MFMA fp16 (f1 -> padded fp16 B-matrix)
  k_f16rows<<<1040,256,0,stream>>>(f1, NG, f1h);
  {
    dim3 grid(CE(NG, BCH), CE(NG, 64));
    k_gemm16<<<grid,256,0,stream>>>(f0, LDF, f1h, nullptr, nullptr, nullptr,
                                    (float*)d_out, 1024, NG, NG, 0, 25.0f);
  }
}